// Round 9
// baseline (403.418 us; speedup 1.0000x reference)
//
#include <hip/hip_runtime.h>
#include <hip/hip_cooperative_groups.h>
#include <math.h>

#define B_  8
#define N_  2048
#define D_  768
#define H_  12
#define HD_ 64
#define GB_ 1025
#define LB_ 9
#define NW_ 255

// LDS swizzles (bank-conflict breakers)
#define CBX(i) ((i) + ((i) >> 4))      // padded every 16 elements
#define TWX(i) ((i) + ((i) >> 4))      // twiddle table, same padding

// FFT16 constants
#define C1_ 0.92387953251128674f
#define S1_ 0.38268343236508978f
#define R2_ 0.70710678118654752f

// forward DIF butterflies (twiddle e^{-i*theta}) on yr/yi register arrays
#define FBF(i,k,wr,wi) { const float ar=yr[i],ai=yi[i],br=yr[k],bi=yi[k]; \
  yr[i]=ar+br; yi[i]=ai+bi; const float dr=ar-br, di=ai-bi; \
  yr[k]=fmaf(dr,wr,-(di*(wi))); yi[k]=fmaf(dr,wi,di*(wr)); }
#define FBF1(i,k) { const float ar=yr[i],ai=yi[i],br=yr[k],bi=yi[k]; \
  yr[i]=ar+br; yi[i]=ai+bi; yr[k]=ar-br; yi[k]=ai-bi; }
#define FBFmi(i,k) { const float ar=yr[i],ai=yi[i],br=yr[k],bi=yi[k]; \
  yr[i]=ar+br; yi[i]=ai+bi; yr[k]=ai-bi; yi[k]=br-ar; }

// inverse DIT butterflies (twiddle e^{+i*theta})
#define IBF(i,k,wr,wi) { const float br=yr[k],bi=yi[k]; \
  const float tr=fmaf(br,wr,-(bi*(wi))), ti=fmaf(br,wi,bi*(wr)); \
  yr[k]=yr[i]-tr; yi[k]=yi[i]-ti; yr[i]+=tr; yi[i]+=ti; }
#define IBF1(i,k) { const float tr=yr[k], ti=yi[k]; \
  yr[k]=yr[i]-tr; yi[k]=yi[i]-ti; yr[i]+=tr; yi[i]+=ti; }
#define IBFpi(i,k) { const float tr=-yi[k], ti=yr[k]; \
  yr[k]=yr[i]-tr; yi[k]=yi[i]-ti; yr[i]+=tr; yi[i]+=ti; }

__device__ __forceinline__ float2 cmulf(float2 a, float2 b) {
  return make_float2(fmaf(a.x, b.x, -(a.y*b.y)), fmaf(a.x, b.y, a.y*b.x));
}
__device__ __forceinline__ float2 csqf(float2 a){ return make_float2(fmaf(a.x,a.x,-(a.y*a.y)), 2.0f*a.x*a.y); }

// ---- dual packed complex (float4 = two complexes sharing one twiddle) ----
__device__ __forceinline__ float4 dadd(float4 a, float4 b){ return make_float4(a.x+b.x,a.y+b.y,a.z+b.z,a.w+b.w); }
__device__ __forceinline__ float4 dsub(float4 a, float4 b){ return make_float4(a.x-b.x,a.y-b.y,a.z-b.z,a.w-b.w); }
__device__ __forceinline__ float4 dmul(float4 a, float2 w){
  return make_float4(fmaf(a.x,w.x,-(a.y*w.y)), fmaf(a.x,w.y,a.y*w.x),
                     fmaf(a.z,w.x,-(a.w*w.y)), fmaf(a.z,w.y,a.w*w.x));
}
__device__ __forceinline__ float4 dmulc(float4 a, float2 w){   // * conj(w)
  return make_float4(fmaf(a.x,w.x,a.y*w.y), fmaf(a.y,w.x,-(a.x*w.y)),
                     fmaf(a.z,w.x,a.w*w.y), fmaf(a.w,w.x,-(a.z*w.y)));
}
__device__ __forceinline__ float4 dmuli(float4 a){  // * (-i)
  return make_float4(a.y, -a.x, a.w, -a.z);
}
__device__ __forceinline__ float4 dmulpi(float4 a){ // * (+i)
  return make_float4(-a.y, a.x, -a.w, a.z);
}

// modrelu helpers: native v_sqrt/v_rcp instead of precise-div chains
__device__ __forceinline__ void mr2(float& ar, float& ai, float filt, float bias){
  ar *= filt; ai *= filt;
  const float a = __builtin_amdgcn_sqrtf(fmaf(ar,ar,ai*ai));
  const float s = fmaxf(a + bias, 0.0f) * __builtin_amdgcn_rcpf(fmaxf(a, 1e-6f));
  ar *= s; ai *= s;
}
__device__ __forceinline__ void mr1(float& v, float filt, float bias){
  v *= filt;
  const float a = fabsf(v);
  v *= fmaxf(a + bias, 0.0f) * __builtin_amdgcn_rcpf(fmaxf(a, 1e-6f));
}

// ---- register FFT trips (dual): 3 radix-2 stages (spans 4S,2S,S) on the
// stride-S 8-value set owned by thread j. One tw read per trip; other
// twiddles derived exactly (c8 = e^{-i pi/4}, w^2, w^4, *(-i) free).
template<int S, int L>
__device__ __forceinline__ void fft_trip_fwd(float4* cb, const float2* tw, int j) {
  const int r    = j & (S-1);
  const int base = r + ((j >> L) << (L+3));
  float4 v[8];
  #pragma unroll
  for (int k = 0; k < 8; ++k) v[k] = cb[CBX(base + S*k)];
  const float2 w = tw[TWX(r * (256/S))];
  const float2 c8 = make_float2(R2_, -R2_);
  float2 W1[4];
  W1[0] = w;
  W1[1] = cmulf(w, c8);
  W1[2] = make_float2(w.y, -w.x);
  W1[3] = make_float2(W1[1].y, -W1[1].x);
  #pragma unroll
  for (int k = 0; k < 4; ++k) {
    const float4 u = v[k], t = v[k+4];
    v[k]   = dadd(u, t);
    v[k+4] = dmul(dsub(u, t), W1[k]);
  }
  const float2 w2  = csqf(w);
  const float2 w2i = make_float2(w2.y, -w2.x);
  {
    float4 d;
    d = dsub(v[0], v[2]); v[0] = dadd(v[0], v[2]); v[2] = dmul(d, w2);
    d = dsub(v[1], v[3]); v[1] = dadd(v[1], v[3]); v[3] = dmul(d, w2i);
    d = dsub(v[4], v[6]); v[4] = dadd(v[4], v[6]); v[6] = dmul(d, w2);
    d = dsub(v[5], v[7]); v[5] = dadd(v[5], v[7]); v[7] = dmul(d, w2i);
  }
  const float2 w4 = csqf(w2);
  #pragma unroll
  for (int k = 0; k < 8; k += 2) {
    const float4 d = dsub(v[k], v[k+1]);
    v[k]   = dadd(v[k], v[k+1]);
    v[k+1] = dmul(d, w4);
  }
  #pragma unroll
  for (int k = 0; k < 8; ++k) cb[CBX(base + S*k)] = v[k];
}

// final forward trip: spans 2,1 on 8 consecutive values (twiddle-free)
__device__ __forceinline__ void fft_trip4_fwd(float4* cb, int j) {
  const int base = j << 3;
  float4 v[8];
  #pragma unroll
  for (int k = 0; k < 8; ++k) v[k] = cb[CBX(base + k)];
  float4 d;
  d = dsub(v[0], v[2]); v[0] = dadd(v[0], v[2]); v[2] = d;
  d = dsub(v[1], v[3]); v[1] = dadd(v[1], v[3]); v[3] = dmuli(d);
  d = dsub(v[4], v[6]); v[4] = dadd(v[4], v[6]); v[6] = d;
  d = dsub(v[5], v[7]); v[5] = dadd(v[5], v[7]); v[7] = dmuli(d);
  #pragma unroll
  for (int k = 0; k < 8; k += 2) {
    d = dsub(v[k], v[k+1]);
    v[k]   = dadd(v[k], v[k+1]);
    v[k+1] = d;
  }
  #pragma unroll
  for (int k = 0; k < 8; ++k) cb[CBX(base + k)] = v[k];
}

// first inverse trip: spans 1,2 (conj twiddles trivial: 1, +i)
__device__ __forceinline__ void fft_trip1_inv(float4* cb, int j) {
  const int base = j << 3;
  float4 v[8];
  #pragma unroll
  for (int k = 0; k < 8; ++k) v[k] = cb[CBX(base + k)];
  #pragma unroll
  for (int k = 0; k < 8; k += 2) {
    const float4 t = v[k+1];
    v[k+1] = dsub(v[k], t);
    v[k]   = dadd(v[k], t);
  }
  {
    float4 t;
    t = v[2];          v[2] = dsub(v[0], t); v[0] = dadd(v[0], t);
    t = dmulpi(v[3]);  v[3] = dsub(v[1], t); v[1] = dadd(v[1], t);
    t = v[6];          v[6] = dsub(v[4], t); v[4] = dadd(v[4], t);
    t = dmulpi(v[7]);  v[7] = dsub(v[5], t); v[5] = dadd(v[5], t);
  }
  #pragma unroll
  for (int k = 0; k < 8; ++k) cb[CBX(base + k)] = v[k];
}

template<int S, int L>
__device__ __forceinline__ void fft_trip_inv(float4* cb, const float2* tw, int j) {
  const int r    = j & (S-1);
  const int base = r + ((j >> L) << (L+3));
  float4 v[8];
  #pragma unroll
  for (int k = 0; k < 8; ++k) v[k] = cb[CBX(base + S*k)];
  const float2 w  = tw[TWX(r * (256/S))];
  const float2 w2 = csqf(w);
  const float2 w4 = csqf(w2);
  #pragma unroll
  for (int k = 0; k < 8; k += 2) {
    const float4 t = dmulc(v[k+1], w4);
    v[k+1] = dsub(v[k], t);
    v[k]   = dadd(v[k], t);
  }
  {
    float4 t;
    t = dmulc(v[2], w2);          v[2] = dsub(v[0], t); v[0] = dadd(v[0], t);
    t = dmulpi(dmulc(v[3], w2));  v[3] = dsub(v[1], t); v[1] = dadd(v[1], t);
    t = dmulc(v[6], w2);          v[6] = dsub(v[4], t); v[4] = dadd(v[4], t);
    t = dmulpi(dmulc(v[7], w2));  v[7] = dsub(v[5], t); v[5] = dadd(v[5], t);
  }
  const float2 c8 = make_float2(R2_, -R2_);
  float2 W1[4];
  W1[0] = w;
  W1[1] = cmulf(w, c8);
  W1[2] = make_float2(w.y, -w.x);
  W1[3] = make_float2(W1[1].y, -W1[1].x);
  #pragma unroll
  for (int k = 0; k < 4; ++k) {
    const float4 t = dmulc(v[k+4], W1[k]);
    v[k+4] = dsub(v[k], t);
    v[k]   = dadd(v[k], t);
  }
  #pragma unroll
  for (int k = 0; k < 8; ++k) cb[CBX(base + S*k)] = v[k];
}

// ---- local windowed FFT16 path for one packed half (HALF=0 -> .xy, 1 -> .zw)
template<int HALF>
__device__ __forceinline__ void local_path(const float4* cb, const float* lf, const float* lb,
                                           int tid, float* w1a, float* w2a) {
  const float HWIN[16] = {0.0f, 0.038060233744356624f, 0.14644660940672624f, 0.30865828381745508f,
                          0.5f, 0.69134171618254492f, 0.85355339059327376f, 0.96193976625564337f,
                          1.0f, 0.96193976625564337f, 0.85355339059327376f, 0.69134171618254492f,
                          0.5f, 0.30865828381745508f, 0.14644660940672624f, 0.038060233744356624f};
  if (tid < NW_) {
    float yr[16], yi[16];
    #pragma unroll
    for (int t = 0; t < 16; ++t) {
      const float4 v = cb[CBX(tid*8 + t)];
      yr[t] = (HALF ? v.z : v.x) * HWIN[t];
      yi[t] = (HALF ? v.w : v.y) * HWIN[t];
    }
    // forward FFT16 (DIF, natural -> bitrev)
    FBF1(0,8); FBF(1,9,C1_,-S1_); FBF(2,10,R2_,-R2_); FBF(3,11,S1_,-C1_);
    FBFmi(4,12); FBF(5,13,-S1_,-C1_); FBF(6,14,-R2_,-R2_); FBF(7,15,-C1_,-S1_);
    FBF1(0,4); FBF(1,5,R2_,-R2_); FBFmi(2,6); FBF(3,7,-R2_,-R2_);
    FBF1(8,12); FBF(9,13,R2_,-R2_); FBFmi(10,14); FBF(11,15,-R2_,-R2_);
    FBF1(0,2); FBFmi(1,3); FBF1(4,6); FBFmi(5,7);
    FBF1(8,10); FBFmi(9,11); FBF1(12,14); FBFmi(13,15);
    FBF1(0,1); FBF1(2,3); FBF1(4,5); FBF1(6,7);
    FBF1(8,9); FBF1(10,11); FBF1(12,13); FBF1(14,15);
    // separate F1/F2 (bitrev), filter+modrelu, repack W (bitrev)
    {
      const int IA[9] = {0,8,4,12,2,10,6,14,1};
      const int IB[9] = {0,15,7,11,3,13,5,9,1};
      #pragma unroll
      for (int l = 0; l <= 8; ++l) {
        const int ia = IA[l], ib = IB[l];
        const float Zar=yr[ia], Zai=yi[ia], Zbr=yr[ib], Zbi=yi[ib];
        float f1r = 0.125f*(Zar+Zbr), f1i = 0.125f*(Zai-Zbi);
        float f2r = 0.125f*(Zai+Zbi), f2i = 0.125f*(Zbr-Zar);
        const float ft = lf[l], bs = lb[l];
        mr2(f1r, f1i, ft, bs);
        mr2(f2r, f2i, ft, bs);
        yr[ia] = f1r - f2i; yi[ia] = f1i + f2r;
        if (l >= 1 && l <= 7) { yr[ib] = f1r + f2i; yi[ib] = f2r - f1i; }
      }
    }
    // inverse FFT16 (DIT, bitrev -> natural)
    IBF1(0,1); IBF1(2,3); IBF1(4,5); IBF1(6,7);
    IBF1(8,9); IBF1(10,11); IBF1(12,13); IBF1(14,15);
    IBF1(0,2); IBFpi(1,3); IBF1(4,6); IBFpi(5,7);
    IBF1(8,10); IBFpi(9,11); IBF1(12,14); IBFpi(13,15);
    IBF1(0,4); IBF(1,5,R2_,R2_); IBFpi(2,6); IBF(3,7,-R2_,R2_);
    IBF1(8,12); IBF(9,13,R2_,R2_); IBFpi(10,14); IBF(11,15,-R2_,R2_);
    IBF1(0,8); IBF(1,9,C1_,S1_); IBF(2,10,R2_,R2_); IBF(3,11,S1_,C1_);
    IBFpi(4,12); IBF(5,13,-S1_,C1_); IBF(6,14,-R2_,R2_); IBF(7,15,-C1_,S1_);
    #pragma unroll
    for (int t = 0; t < 16; ++t) {
      const float q = 0.25f * HWIN[t];
      w1a[t] = yr[t] * q;
      w2a[t] = yi[t] * q;
    }
  } else {
    #pragma unroll
    for (int t = 0; t < 16; ++t) { w1a[t] = 0.0f; w2a[t] = 0.0f; }
  }
}

__device__ __forceinline__ void combine_oa(const float* w1a, const float* w2a,
                                           const float (*t1)[8], const float (*t2)[8],
                                           int lane, int wvi, float* r1, float* r2) {
  #pragma unroll
  for (int s = 0; s < 8; ++s) {
    float p1 = __shfl_up(w1a[s+8], 1, 64);
    float p2 = __shfl_up(w2a[s+8], 1, 64);
    if (lane == 0) {
      p1 = wvi ? t1[wvi-1][s] : 0.0f;
      p2 = wvi ? t2[wvi-1][s] : 0.0f;
    }
    r1[s] = w1a[s] + p1;
    r2[s] = w2a[s] + p2;
  }
}

// ---------------------------------------------------------------- fused MLP chain
// ONE cooperative kernel replaces memset + k_ctx + k_mlp1 + k_mlp2 (4 graph
// nodes -> 1). 256 blocks co-resident (33 KB LDS, 1 block/CU trivially).
//   Phase A: non-atomic ctx partials (kills memset AND atomic contention)
//   Phase B: batch-split mlp1; per-block fold of 32 partials (98 KB, L2-hot,
//            192-way parallel -- 8x more parallel than the R5 variant)
//   Phase C: mlp2 (195 working blocks)
__global__ __launch_bounds__(256) void k_mlpchain(
    const float* __restrict__ x,
    const float* __restrict__ w1g, const float* __restrict__ b1g,
    const float* __restrict__ w1l, const float* __restrict__ b1l,
    const float* __restrict__ w2g, const float* __restrict__ b2g,
    const float* __restrict__ w2l, const float* __restrict__ b2l,
    float* __restrict__ ctxp, float* __restrict__ h1g, float* __restrict__ h1l,
    float* __restrict__ mg, float* __restrict__ ml) {
  cooperative_groups::grid_group grid = cooperative_groups::this_grid();
  __shared__ float hs[B_*D_];
  __shared__ float red[4][16][33];
  const int tid = threadIdx.x;
  const int bid = blockIdx.x;

  // ---- phase A: ctx partial sums (block = (b, 64-row chunk)) ----
  {
    const int b  = bid >> 5;
    const int nc = bid & 31;
    const int n0 = nc * 64;
    for (int c = tid; c < D_; c += 256) {
      float s = 0.0f;
      #pragma unroll 4
      for (int n = 0; n < 64; ++n)
        s += x[((size_t)(b*N_ + n0 + n))*D_ + c];
      ctxp[(size_t)(nc*B_ + b)*D_ + c] = s;
    }
  }
  __threadfence();
  grid.sync();

  // ---- phase B: mlp1 (gelu), 192 working blocks ----
  if (bid < 192) {
    const int jx   = bid % 12;
    const int rest = bid / 12;
    const bool isl = (rest & 1) != 0;
    const int bb   = rest >> 1;
    const float* w1 = isl ? w1l : w1g;
    const float* b1 = isl ? b1l : b1g;
    float*       h1 = isl ? h1l : h1g;
    const int j0 = jx * 64;

    for (int i = tid; i < D_; i += 256) {
      float s = 0.0f;
      #pragma unroll 8
      for (int p = 0; p < 32; ++p)
        s += ctxp[(size_t)p*(B_*D_) + bb*D_ + i];
      hs[i] = s * (1.0f/(float)N_);
    }
    __syncthreads();

    const int jg    = tid & 15;
    const int slice = tid >> 4;
    const int j     = j0 + jg*4;
    float acc[4] = {};
    {
      const float4* w14 = (const float4*)w1;
      const int jc = j >> 2;
      const int i0 = slice*48;
      #pragma unroll 4
      for (int ii = 0; ii < 48; ++ii) {
        const int i = i0 + ii;
        const float4 w = w14[(size_t)i*192 + jc];
        const float hv = hs[i];
        acc[0] = fmaf(hv, w.x, acc[0]);
        acc[1] = fmaf(hv, w.y, acc[1]);
        acc[2] = fmaf(hv, w.z, acc[2]);
        acc[3] = fmaf(hv, w.w, acc[3]);
      }
    }
    #pragma unroll
    for (int q = 0; q < 4; ++q) {
      float v = acc[q];
      v += __shfl_xor(v, 16, 64);
      v += __shfl_xor(v, 32, 64);
      acc[q] = v;
    }
    const int wv = tid >> 6;
    if ((tid & 63) < 16) {
      #pragma unroll
      for (int q = 0; q < 4; ++q)
        red[wv][jg][q] = acc[q];
    }
    __syncthreads();
    if (tid < 64) {
      const int jg2 = tid >> 2;
      const int q   = tid & 3;
      const int jo  = j0 + jg2*4 + q;
      const float sum = red[0][jg2][q] + red[1][jg2][q]
                      + red[2][jg2][q] + red[3][jg2][q];
      const float v = sum + b1[jo];
      h1[(size_t)bb*D_ + jo] = 0.5f * v * (1.0f + erff(v * 0.70710678118654752f));
    }
  }
  __threadfence();
  grid.sync();

  // ---- phase C: mlp2 (tanh), 195 working blocks ----
  if (bid < 195) {
    const bool isg = (bid < 193);
    const float* h1 = isg ? h1g : h1l;
    const float* w2 = isg ? w2g : w2l;
    const float* b2 = isg ? b2g : b2l;
    float*       mo = isg ? mg  : ml;
    const int Jmax = isg ? (H_*GB_) : (H_*LB_);
    const int j0   = isg ? bid*64 : (bid-193)*64;

    for (int i = tid; i < B_*D_; i += 256) hs[i] = h1[i];
    __syncthreads();

    const int jg    = tid & 15;
    const int slice = tid >> 4;
    const int j     = j0 + jg*4;
    float acc[8][4] = {};
    if (j < Jmax) {
      const float4* w24 = (const float4*)w2;
      const int jc   = j >> 2;
      const int rowq = Jmax >> 2;
      const int i0   = slice*48;
      #pragma unroll 4
      for (int ii = 0; ii < 48; ++ii) {
        const int i = i0 + ii;
        const float4 w = w24[(size_t)i*rowq + jc];
        #pragma unroll
        for (int b = 0; b < 8; ++b) {
          const float hv = hs[b*D_ + i];
          acc[b][0] = fmaf(hv, w.x, acc[b][0]);
          acc[b][1] = fmaf(hv, w.y, acc[b][1]);
          acc[b][2] = fmaf(hv, w.z, acc[b][2]);
          acc[b][3] = fmaf(hv, w.w, acc[b][3]);
        }
      }
    }
    #pragma unroll
    for (int b = 0; b < 8; ++b) {
      #pragma unroll
      for (int q = 0; q < 4; ++q) {
        float v = acc[b][q];
        v += __shfl_xor(v, 16, 64);
        v += __shfl_xor(v, 32, 64);
        acc[b][q] = v;
      }
    }
    const int wv = tid >> 6;
    if ((tid & 63) < 16) {
      #pragma unroll
      for (int b = 0; b < 8; ++b)
        #pragma unroll
        for (int q = 0; q < 4; ++q)
          red[wv][jg][b*4+q] = acc[b][q];
    }
    __syncthreads();
    for (int s = tid; s < 512; s += 256) {
      const int jg2 = s >> 5;
      const int v2  = s & 31;
      const int b   = v2 >> 2, q = v2 & 3;
      const int jo  = j0 + jg2*4 + q;
      if (jo < Jmax) {
        const float sum = red[0][jg2][v2] + red[1][jg2][v2]
                        + red[2][jg2][v2] + red[3][jg2][v2];
        mo[(size_t)b*Jmax + jo] = tanhf(sum + b2[jo]);
      }
    }
  }
}

// ---------------------------------------------------------------- spectral
// One block per COLUMN QUAD. Output includes the RESIDUAL (re-reads x in the
// store phase); fused written in [cg][n][4] layout.
__global__ __launch_bounds__(256) void k_spectral(
    const float* __restrict__ x,
    const float* __restrict__ bfg, const float* __restrict__ bfl,
    const float* __restrict__ mbg, const float* __restrict__ mbl,
    const float* __restrict__ mg,  const float* __restrict__ ml,
    const float* __restrict__ fw,  float* __restrict__ fused) {
  __shared__ float4 cb[N_ + (N_>>4)];       // dual complex, swizzled (34.8 KB)
  __shared__ float2 tw[256 + 16];           // tw[TWX(m)] = exp(-i*pi*m/1024)
  __shared__ float  t1b[2][4][8], t2b[2][4][8];
  __shared__ float  lf[LB_], lb[LB_];

  const int tid = threadIdx.x;
  const int id  = blockIdx.x;               // 1536
  const int v_  = (id & 7) * 192 + (id >> 3);   // XCD-resident remap (1536/8=192)
  const int dq  = v_ & 15;
  const int bh  = v_ >> 4;
  const int h   = bh % H_;
  const int b   = bh / H_;
  const int d   = dq * 4;
  const int c   = h*HD_ + d;
  const int cg  = bh*16 + dq;               // channel-quad index

  {
    float s_, c_;
    sincospif(-(float)tid * (1.0f/1024.0f), &s_, &c_);
    tw[TWX(tid)] = make_float2(c_, s_);
  }
  if (tid < LB_) {
    lf[tid] = bfl[h*LB_ + tid] + ml[(size_t)b*(H_*LB_) + h*LB_ + tid];
    lb[tid] = mbl[h*LB_ + tid];
  }
  const float* xp = &x[((size_t)(b*N_))*D_ + c];
  for (int n = tid; n < N_; n += 256) {
    cb[CBX(n)] = *(const float4*)&xp[(size_t)n*D_];
  }
  __syncthreads();

  // ---- local windowed path (cb still holds raw x); two sequential passes ----
  const int lane = tid & 63, wvi = tid >> 6;
  float r1[8], r2[8], r3[8], r4[8];
  {
    float w1a[16], w2a[16];
    local_path<0>(cb, lf, lb, tid, w1a, w2a);
    if (lane == 63 && tid < NW_) {
      #pragma unroll
      for (int s = 0; s < 8; ++s) { t1b[0][wvi][s] = w1a[8+s]; t2b[0][wvi][s] = w2a[8+s]; }
    }
    __syncthreads();
    combine_oa(w1a, w2a, t1b[0], t2b[0], lane, wvi, r1, r2);
  }
  {
    float w1a[16], w2a[16];
    local_path<1>(cb, lf, lb, tid, w1a, w2a);
    if (lane == 63 && tid < NW_) {
      #pragma unroll
      for (int s = 0; s < 8; ++s) { t1b[1][wvi][s] = w1a[8+s]; t2b[1][wvi][s] = w2a[8+s]; }
    }
    __syncthreads();   // also guarantees all raw-x reads done before FFT writes
    combine_oa(w1a, w2a, t1b[1], t2b[1], lane, wvi, r3, r4);
  }

  // ---- forward FFT: 4 register trips (natural in -> bitrev out) ----
  fft_trip_fwd<256,8>(cb, tw, tid); __syncthreads();
  fft_trip_fwd< 32,5>(cb, tw, tid); __syncthreads();
  fft_trip_fwd<  4,2>(cb, tw, tid); __syncthreads();
  fft_trip4_fwd(cb, tid);           __syncthreads();

  // ---- separate packed spectra, filter+modrelu, repack (bitrev domain) ----
  const float fsc = 0.022097086912079610f;   // 1/sqrt(2048)
  {
    const float* mgp = mg + (size_t)b*(H_*GB_) + h*GB_;
    const float* bfp = bfg + h*GB_;
    const float* mbp = mbg + h*GB_;
    const int kb = (tid & 192) + (int)(__brev((unsigned)(tid & 63)) >> 26);  // brev6 lane permute
    #pragma unroll
    for (int t = 0; t < 4; ++t) {
      const int k = kb + 256*t;
      if (k == 0) {
        float4 Z0 = cb[CBX(0)], Zn = cb[CBX(1)];
        const float f0t = bfp[0] + mgp[0],     b0 = mbp[0];
        const float fnt = bfp[1024] + mgp[1024], bn = mbp[1024];
        float a0 = Z0.x*fsc, a1 = Z0.y*fsc, a2 = Z0.z*fsc, a3 = Z0.w*fsc;
        mr1(a0, f0t, b0); mr1(a1, f0t, b0); mr1(a2, f0t, b0); mr1(a3, f0t, b0);
        cb[CBX(0)] = make_float4(a0, a1, a2, a3);
        float n0v = Zn.x*fsc, n1v = Zn.y*fsc, n2v = Zn.z*fsc, n3v = Zn.w*fsc;
        mr1(n0v, fnt, bn); mr1(n1v, fnt, bn); mr1(n2v, fnt, bn); mr1(n3v, fnt, bn);
        cb[CBX(1)] = make_float4(n0v, n1v, n2v, n3v);
      } else {
        const int ik  = (int)(__brev((unsigned)k) >> 21);
        const int imk = (int)(__brev((unsigned)(2048 - k)) >> 21);
        const float4 Za = cb[CBX(ik)], Zb = cb[CBX(imk)];
        const float hs_ = 0.5f * fsc;
        const float filt = bfp[k] + mgp[k], bias = mbp[k];
        // pair 0 (.x,.y)
        float f1r = (Za.x + Zb.x) * hs_, f1i = (Za.y - Zb.y) * hs_;
        float f2r = (Za.y + Zb.y) * hs_, f2i = (Zb.x - Za.x) * hs_;
        mr2(f1r, f1i, filt, bias);
        mr2(f2r, f2i, filt, bias);
        // pair 1 (.z,.w)
        float g1r = (Za.z + Zb.z) * hs_, g1i = (Za.w - Zb.w) * hs_;
        float g2r = (Za.w + Zb.w) * hs_, g2i = (Zb.z - Za.z) * hs_;
        mr2(g1r, g1i, filt, bias);
        mr2(g2r, g2i, filt, bias);
        cb[CBX(ik)]  = make_float4(f1r - f2i, f1i + f2r, g1r - g2i, g1i + g2r);
        cb[CBX(imk)] = make_float4(f1r + f2i, f2r - f1i, g1r + g2i, g2r - g1i);
      }
    }
  }
  __syncthreads();

  // ---- inverse FFT: 4 register trips (bitrev in -> natural out) ----
  fft_trip1_inv(cb, tid);           __syncthreads();
  fft_trip_inv<  4,2>(cb, tw, tid); __syncthreads();
  fft_trip_inv< 32,5>(cb, tw, tid); __syncthreads();
  fft_trip_inv<256,8>(cb, tw, tid); __syncthreads();

  // ---- fuse + residual + store: thread j owns n in [8j, 8j+8) ----
  const float fw1v = fw[1];
  const float fwg  = fw[0] * fsc;
  float4* fo = (float4*)fused + (size_t)cg * N_;
  const int n0 = tid * 8;
  #pragma unroll
  for (int s = 0; s < 8; ++s) {
    const float4 g  = cb[CBX(n0 + s)];
    const float4 xv = *(const float4*)&xp[(size_t)(n0 + s)*D_];
    fo[n0 + s] = make_float4(xv.x + fwg * g.x + fw1v * r1[s],
                             xv.y + fwg * g.y + fw1v * r2[s],
                             xv.z + fwg * g.z + fw1v * r3[s],
                             xv.w + fwg * g.w + fw1v * r4[s]);
  }
}

// ---------------------------------------------------------------- LayerNorm
// fused already contains x + combined spectral output (residual done in
// k_spectral). 3 phases: load(transposed) -> row stats -> normalize.
__global__ __launch_bounds__(256) void k_ln(const float* __restrict__ fused,
                                            const float* __restrict__ gamma,
                                            const float* __restrict__ beta,
                                            float* __restrict__ out) {
  __shared__ float yt[16*776];     // stride 776: 776%32==8 -> limited conflicts
  __shared__ float mus[16], rsd[16];
  const int bi = blockIdx.x;
  const int b  = bi >> 7;
  const int n0 = (bi & 127) * 16;
  const int tid = threadIdx.x;

  {
    // fused layout [cg][n][4]: 16 consecutive threads read 256 B contiguous
    const float4* fu4 = (const float4*)fused;
    for (int i = tid; i < 16*192; i += 256) {
      const int cgl = i >> 4, rn = i & 15;
      const float4 g = fu4[((size_t)(b*192 + cgl))*N_ + n0 + rn];
      float* yp = &yt[rn*776 + cgl*4];
      yp[0] = g.x; yp[1] = g.y; yp[2] = g.z; yp[3] = g.w;
    }
  }
  __syncthreads();
  const int nn = tid >> 4, cl = tid & 15;
  float s1 = 0.0f, s2 = 0.0f;
  for (int c = cl; c < D_; c += 16) {
    const float v = yt[nn*776 + c];
    s1 += v; s2 += v*v;
  }
  #pragma unroll
  for (int m = 8; m >= 1; m >>= 1) {
    s1 += __shfl_xor(s1, m, 16);
    s2 += __shfl_xor(s2, m, 16);
  }
  if (cl == 0) {
    const float mu  = s1 * (1.0f/(float)D_);
    const float var = s2 * (1.0f/(float)D_) - mu*mu;
    mus[nn] = mu;
    rsd[nn] = rsqrtf(var + 1e-5f);
  }
  __syncthreads();
  {
    float4* o4 = (float4*)(out + ((size_t)(b*N_ + n0))*D_);
    const float4* g4 = (const float4*)gamma;
    const float4* be4 = (const float4*)beta;
    for (int i = tid; i < 16*D_/4; i += 256) {
      const int nn2 = i / 192, r = i - nn2*192;
      const float mu = mus[nn2], rs = rsd[nn2];
      const float4 gm = g4[r], bt = be4[r];
      const float* yp = &yt[nn2*776 + r*4];
      float4 o;
      o.x = (yp[0] - mu) * rs * gm.x + bt.x;
      o.y = (yp[1] - mu) * rs * gm.y + bt.y;
      o.z = (yp[2] - mu) * rs * gm.z + bt.z;
      o.w = (yp[3] - mu) * rs * gm.w + bt.w;
      o4[i] = o;
    }
  }
}

// ---------------------------------------------------------------- launch
extern "C" void kernel_launch(void* const* d_in, const int* in_sizes, int n_in,
                              void* d_out, int out_size, void* d_ws, size_t ws_size,
                              hipStream_t stream) {
  const float* x   = (const float*)d_in[0];
  const float* bfg = (const float*)d_in[1];
  const float* bfl = (const float*)d_in[2];
  const float* mbg = (const float*)d_in[3];
  const float* mbl = (const float*)d_in[4];
  const float* w1g = (const float*)d_in[5];
  const float* b1g = (const float*)d_in[6];
  const float* w2g = (const float*)d_in[7];
  const float* b2g = (const float*)d_in[8];
  const float* w1l = (const float*)d_in[9];
  const float* b1l = (const float*)d_in[10];
  const float* w2l = (const float*)d_in[11];
  const float* b2l = (const float*)d_in[12];
  const float* fw  = (const float*)d_in[13];
  const float* gam = (const float*)d_in[14];
  const float* bet = (const float*)d_in[15];
  float* out = (float*)d_out;

  float* ws    = (float*)d_ws;
  float* h1g   = ws + 6144;
  float* h1l   = ws + 12288;
  float* mg    = ws + 18432;         // 98400
  float* ml    = ws + 116832;        // 864
  float* fused = ws + 117696;        // 8*768*2048
  // ctxp (32 partials x B x D = 196608 floats) aliases the head of `fused`:
  // fully consumed inside k_mlpchain BEFORE k_spectral writes fused.
  float* ctxp  = fused;

  {
    void* args[] = { (void*)&x,
                     (void*)&w1g, (void*)&b1g, (void*)&w1l, (void*)&b1l,
                     (void*)&w2g, (void*)&b2g, (void*)&w2l, (void*)&b2l,
                     (void*)&ctxp, (void*)&h1g, (void*)&h1l, (void*)&mg, (void*)&ml };
    hipLaunchCooperativeKernel((const void*)k_mlpchain, dim3(256), dim3(256),
                               args, 0, stream);
  }
  k_spectral<<<B_*H_*16, 256, 0, stream>>>(x, bfg, bfl, mbg, mbl, mg, ml, fw, fused);
  k_ln<<<B_*N_/16, 256, 0, stream>>>(fused, gam, bet, out);
}

// Round 10
// 283.034 us; speedup vs baseline: 1.4253x; 1.4253x over previous
//
#include <hip/hip_runtime.h>
#include <math.h>

#define B_  8
#define N_  2048
#define D_  768
#define H_  12
#define HD_ 64
#define GB_ 1025
#define LB_ 9
#define NW_ 255

// LDS swizzles (bank-conflict breakers)
#define CBX(i) ((i) + ((i) >> 4))      // padded every 16 elements
#define TWX(i) ((i) + ((i) >> 4))      // twiddle table, same padding

// FFT16 constants
#define C1_ 0.92387953251128674f
#define S1_ 0.38268343236508978f
#define R2_ 0.70710678118654752f

// forward DIF butterflies (twiddle e^{-i*theta}) on yr/yi register arrays
#define FBF(i,k,wr,wi) { const float ar=yr[i],ai=yi[i],br=yr[k],bi=yi[k]; \
  yr[i]=ar+br; yi[i]=ai+bi; const float dr=ar-br, di=ai-bi; \
  yr[k]=fmaf(dr,wr,-(di*(wi))); yi[k]=fmaf(dr,wi,di*(wr)); }
#define FBF1(i,k) { const float ar=yr[i],ai=yi[i],br=yr[k],bi=yi[k]; \
  yr[i]=ar+br; yi[i]=ai+bi; yr[k]=ar-br; yi[k]=ai-bi; }
#define FBFmi(i,k) { const float ar=yr[i],ai=yi[i],br=yr[k],bi=yi[k]; \
  yr[i]=ar+br; yi[i]=ai+bi; yr[k]=ai-bi; yi[k]=br-ar; }

// inverse DIT butterflies (twiddle e^{+i*theta})
#define IBF(i,k,wr,wi) { const float br=yr[k],bi=yi[k]; \
  const float tr=fmaf(br,wr,-(bi*(wi))), ti=fmaf(br,wi,bi*(wr)); \
  yr[k]=yr[i]-tr; yi[k]=yi[i]-ti; yr[i]+=tr; yi[i]+=ti; }
#define IBF1(i,k) { const float tr=yr[k], ti=yi[k]; \
  yr[k]=yr[i]-tr; yi[k]=yi[i]-ti; yr[i]+=tr; yi[i]+=ti; }
#define IBFpi(i,k) { const float tr=-yi[k], ti=yr[k]; \
  yr[k]=yr[i]-tr; yi[k]=yi[i]-ti; yr[i]+=tr; yi[i]+=ti; }

__device__ __forceinline__ float2 cmulf(float2 a, float2 b) {
  return make_float2(fmaf(a.x, b.x, -(a.y*b.y)), fmaf(a.x, b.y, a.y*b.x));
}
__device__ __forceinline__ float2 csqf(float2 a){ return make_float2(fmaf(a.x,a.x,-(a.y*a.y)), 2.0f*a.x*a.y); }

// ---- dual packed complex (float4 = two complexes sharing one twiddle) ----
__device__ __forceinline__ float4 dadd(float4 a, float4 b){ return make_float4(a.x+b.x,a.y+b.y,a.z+b.z,a.w+b.w); }
__device__ __forceinline__ float4 dsub(float4 a, float4 b){ return make_float4(a.x-b.x,a.y-b.y,a.z-b.z,a.w-b.w); }
__device__ __forceinline__ float4 dmul(float4 a, float2 w){
  return make_float4(fmaf(a.x,w.x,-(a.y*w.y)), fmaf(a.x,w.y,a.y*w.x),
                     fmaf(a.z,w.x,-(a.w*w.y)), fmaf(a.z,w.y,a.w*w.x));
}
__device__ __forceinline__ float4 dmulc(float4 a, float2 w){   // * conj(w)
  return make_float4(fmaf(a.x,w.x,a.y*w.y), fmaf(a.y,w.x,-(a.x*w.y)),
                     fmaf(a.z,w.x,a.w*w.y), fmaf(a.w,w.x,-(a.z*w.y)));
}
__device__ __forceinline__ float4 dmuli(float4 a){  // * (-i)
  return make_float4(a.y, -a.x, a.w, -a.z);
}
__device__ __forceinline__ float4 dmulpi(float4 a){ // * (+i)
  return make_float4(-a.y, a.x, -a.w, a.z);
}

// modrelu helpers: native v_sqrt/v_rcp instead of precise-div chains
__device__ __forceinline__ void mr2(float& ar, float& ai, float filt, float bias){
  ar *= filt; ai *= filt;
  const float a = __builtin_amdgcn_sqrtf(fmaf(ar,ar,ai*ai));
  const float s = fmaxf(a + bias, 0.0f) * __builtin_amdgcn_rcpf(fmaxf(a, 1e-6f));
  ar *= s; ai *= s;
}
__device__ __forceinline__ void mr1(float& v, float filt, float bias){
  v *= filt;
  const float a = fabsf(v);
  v *= fmaxf(a + bias, 0.0f) * __builtin_amdgcn_rcpf(fmaxf(a, 1e-6f));
}

// ---- register FFT trips (dual): 3 radix-2 stages (spans 4S,2S,S) on the
// stride-S 8-value set owned by thread j. One tw read per trip; other
// twiddles derived exactly (c8 = e^{-i pi/4}, w^2, w^4, *(-i) free).
template<int S, int L>
__device__ __forceinline__ void fft_trip_fwd(float4* cb, const float2* tw, int j) {
  const int r    = j & (S-1);
  const int base = r + ((j >> L) << (L+3));
  float4 v[8];
  #pragma unroll
  for (int k = 0; k < 8; ++k) v[k] = cb[CBX(base + S*k)];
  const float2 w = tw[TWX(r * (256/S))];
  const float2 c8 = make_float2(R2_, -R2_);
  float2 W1[4];
  W1[0] = w;
  W1[1] = cmulf(w, c8);
  W1[2] = make_float2(w.y, -w.x);
  W1[3] = make_float2(W1[1].y, -W1[1].x);
  #pragma unroll
  for (int k = 0; k < 4; ++k) {
    const float4 u = v[k], t = v[k+4];
    v[k]   = dadd(u, t);
    v[k+4] = dmul(dsub(u, t), W1[k]);
  }
  const float2 w2  = csqf(w);
  const float2 w2i = make_float2(w2.y, -w2.x);
  {
    float4 d;
    d = dsub(v[0], v[2]); v[0] = dadd(v[0], v[2]); v[2] = dmul(d, w2);
    d = dsub(v[1], v[3]); v[1] = dadd(v[1], v[3]); v[3] = dmul(d, w2i);
    d = dsub(v[4], v[6]); v[4] = dadd(v[4], v[6]); v[6] = dmul(d, w2);
    d = dsub(v[5], v[7]); v[5] = dadd(v[5], v[7]); v[7] = dmul(d, w2i);
  }
  const float2 w4 = csqf(w2);
  #pragma unroll
  for (int k = 0; k < 8; k += 2) {
    const float4 d = dsub(v[k], v[k+1]);
    v[k]   = dadd(v[k], v[k+1]);
    v[k+1] = dmul(d, w4);
  }
  #pragma unroll
  for (int k = 0; k < 8; ++k) cb[CBX(base + S*k)] = v[k];
}

// final forward trip: spans 2,1 on 8 consecutive values (twiddle-free)
__device__ __forceinline__ void fft_trip4_fwd(float4* cb, int j) {
  const int base = j << 3;
  float4 v[8];
  #pragma unroll
  for (int k = 0; k < 8; ++k) v[k] = cb[CBX(base + k)];
  float4 d;
  d = dsub(v[0], v[2]); v[0] = dadd(v[0], v[2]); v[2] = d;
  d = dsub(v[1], v[3]); v[1] = dadd(v[1], v[3]); v[3] = dmuli(d);
  d = dsub(v[4], v[6]); v[4] = dadd(v[4], v[6]); v[6] = d;
  d = dsub(v[5], v[7]); v[5] = dadd(v[5], v[7]); v[7] = dmuli(d);
  #pragma unroll
  for (int k = 0; k < 8; k += 2) {
    d = dsub(v[k], v[k+1]);
    v[k]   = dadd(v[k], v[k+1]);
    v[k+1] = d;
  }
  #pragma unroll
  for (int k = 0; k < 8; ++k) cb[CBX(base + k)] = v[k];
}

// first inverse trip: spans 1,2 (conj twiddles trivial: 1, +i)
__device__ __forceinline__ void fft_trip1_inv(float4* cb, int j) {
  const int base = j << 3;
  float4 v[8];
  #pragma unroll
  for (int k = 0; k < 8; ++k) v[k] = cb[CBX(base + k)];
  #pragma unroll
  for (int k = 0; k < 8; k += 2) {
    const float4 t = v[k+1];
    v[k+1] = dsub(v[k], t);
    v[k]   = dadd(v[k], t);
  }
  {
    float4 t;
    t = v[2];          v[2] = dsub(v[0], t); v[0] = dadd(v[0], t);
    t = dmulpi(v[3]);  v[3] = dsub(v[1], t); v[1] = dadd(v[1], t);
    t = v[6];          v[6] = dsub(v[4], t); v[4] = dadd(v[4], t);
    t = dmulpi(v[7]);  v[7] = dsub(v[5], t); v[5] = dadd(v[5], t);
  }
  #pragma unroll
  for (int k = 0; k < 8; ++k) cb[CBX(base + k)] = v[k];
}

template<int S, int L>
__device__ __forceinline__ void fft_trip_inv(float4* cb, const float2* tw, int j) {
  const int r    = j & (S-1);
  const int base = r + ((j >> L) << (L+3));
  float4 v[8];
  #pragma unroll
  for (int k = 0; k < 8; ++k) v[k] = cb[CBX(base + S*k)];
  const float2 w  = tw[TWX(r * (256/S))];
  const float2 w2 = csqf(w);
  const float2 w4 = csqf(w2);
  #pragma unroll
  for (int k = 0; k < 8; k += 2) {
    const float4 t = dmulc(v[k+1], w4);
    v[k+1] = dsub(v[k], t);
    v[k]   = dadd(v[k], t);
  }
  {
    float4 t;
    t = dmulc(v[2], w2);          v[2] = dsub(v[0], t); v[0] = dadd(v[0], t);
    t = dmulpi(dmulc(v[3], w2));  v[3] = dsub(v[1], t); v[1] = dadd(v[1], t);
    t = dmulc(v[6], w2);          v[6] = dsub(v[4], t); v[4] = dadd(v[4], t);
    t = dmulpi(dmulc(v[7], w2));  v[7] = dsub(v[5], t); v[5] = dadd(v[5], t);
  }
  const float2 c8 = make_float2(R2_, -R2_);
  float2 W1[4];
  W1[0] = w;
  W1[1] = cmulf(w, c8);
  W1[2] = make_float2(w.y, -w.x);
  W1[3] = make_float2(W1[1].y, -W1[1].x);
  #pragma unroll
  for (int k = 0; k < 4; ++k) {
    const float4 t = dmulc(v[k+4], W1[k]);
    v[k+4] = dsub(v[k], t);
    v[k]   = dadd(v[k], t);
  }
  #pragma unroll
  for (int k = 0; k < 8; ++k) cb[CBX(base + S*k)] = v[k];
}

// ---- local windowed FFT16 path for one packed half (HALF=0 -> .xy, 1 -> .zw)
template<int HALF>
__device__ __forceinline__ void local_path(const float4* cb, const float* lf, const float* lb,
                                           int tid, float* w1a, float* w2a) {
  const float HWIN[16] = {0.0f, 0.038060233744356624f, 0.14644660940672624f, 0.30865828381745508f,
                          0.5f, 0.69134171618254492f, 0.85355339059327376f, 0.96193976625564337f,
                          1.0f, 0.96193976625564337f, 0.85355339059327376f, 0.69134171618254492f,
                          0.5f, 0.30865828381745508f, 0.14644660940672624f, 0.038060233744356624f};
  if (tid < NW_) {
    float yr[16], yi[16];
    #pragma unroll
    for (int t = 0; t < 16; ++t) {
      const float4 v = cb[CBX(tid*8 + t)];
      yr[t] = (HALF ? v.z : v.x) * HWIN[t];
      yi[t] = (HALF ? v.w : v.y) * HWIN[t];
    }
    // forward FFT16 (DIF, natural -> bitrev)
    FBF1(0,8); FBF(1,9,C1_,-S1_); FBF(2,10,R2_,-R2_); FBF(3,11,S1_,-C1_);
    FBFmi(4,12); FBF(5,13,-S1_,-C1_); FBF(6,14,-R2_,-R2_); FBF(7,15,-C1_,-S1_);
    FBF1(0,4); FBF(1,5,R2_,-R2_); FBFmi(2,6); FBF(3,7,-R2_,-R2_);
    FBF1(8,12); FBF(9,13,R2_,-R2_); FBFmi(10,14); FBF(11,15,-R2_,-R2_);
    FBF1(0,2); FBFmi(1,3); FBF1(4,6); FBFmi(5,7);
    FBF1(8,10); FBFmi(9,11); FBF1(12,14); FBFmi(13,15);
    FBF1(0,1); FBF1(2,3); FBF1(4,5); FBF1(6,7);
    FBF1(8,9); FBF1(10,11); FBF1(12,13); FBF1(14,15);
    // separate F1/F2 (bitrev), filter+modrelu, repack W (bitrev)
    {
      const int IA[9] = {0,8,4,12,2,10,6,14,1};
      const int IB[9] = {0,15,7,11,3,13,5,9,1};
      #pragma unroll
      for (int l = 0; l <= 8; ++l) {
        const int ia = IA[l], ib = IB[l];
        const float Zar=yr[ia], Zai=yi[ia], Zbr=yr[ib], Zbi=yi[ib];
        float f1r = 0.125f*(Zar+Zbr), f1i = 0.125f*(Zai-Zbi);
        float f2r = 0.125f*(Zai+Zbi), f2i = 0.125f*(Zbr-Zar);
        const float ft = lf[l], bs = lb[l];
        mr2(f1r, f1i, ft, bs);
        mr2(f2r, f2i, ft, bs);
        yr[ia] = f1r - f2i; yi[ia] = f1i + f2r;
        if (l >= 1 && l <= 7) { yr[ib] = f1r + f2i; yi[ib] = f2r - f1i; }
      }
    }
    // inverse FFT16 (DIT, bitrev -> natural)
    IBF1(0,1); IBF1(2,3); IBF1(4,5); IBF1(6,7);
    IBF1(8,9); IBF1(10,11); IBF1(12,13); IBF1(14,15);
    IBF1(0,2); IBFpi(1,3); IBF1(4,6); IBFpi(5,7);
    IBF1(8,10); IBFpi(9,11); IBF1(12,14); IBFpi(13,15);
    IBF1(0,4); IBF(1,5,R2_,R2_); IBFpi(2,6); IBF(3,7,-R2_,R2_);
    IBF1(8,12); IBF(9,13,R2_,R2_); IBFpi(10,14); IBF(11,15,-R2_,R2_);
    IBF1(0,8); IBF(1,9,C1_,S1_); IBF(2,10,R2_,R2_); IBF(3,11,S1_,C1_);
    IBFpi(4,12); IBF(5,13,-S1_,C1_); IBF(6,14,-R2_,R2_); IBF(7,15,-C1_,S1_);
    #pragma unroll
    for (int t = 0; t < 16; ++t) {
      const float q = 0.25f * HWIN[t];
      w1a[t] = yr[t] * q;
      w2a[t] = yi[t] * q;
    }
  } else {
    #pragma unroll
    for (int t = 0; t < 16; ++t) { w1a[t] = 0.0f; w2a[t] = 0.0f; }
  }
}

__device__ __forceinline__ void combine_oa(const float* w1a, const float* w2a,
                                           const float (*t1)[8], const float (*t2)[8],
                                           int lane, int wvi, float* r1, float* r2) {
  #pragma unroll
  for (int s = 0; s < 8; ++s) {
    float p1 = __shfl_up(w1a[s+8], 1, 64);
    float p2 = __shfl_up(w2a[s+8], 1, 64);
    if (lane == 0) {
      p1 = wvi ? t1[wvi-1][s] : 0.0f;
      p2 = wvi ? t2[wvi-1][s] : 0.0f;
    }
    r1[s] = w1a[s] + p1;
    r2[s] = w2a[s] + p2;
  }
}

// ---------------------------------------------------------------- ctx partial sums
// Non-atomic partials (no memset node needed). Identical loop cost to the
// atomic version; the 32-partial fold happens in the 192-block batch-split
// mlp1 (98 KB per block, coalesced) -- NOT R5's serial 24-block fold.
__global__ __launch_bounds__(256) void k_ctx(const float* __restrict__ x,
                                             float* __restrict__ ctxp) {
  const int b = blockIdx.x;
  const int nc = blockIdx.y;
  const int tid = threadIdx.x;
  const int n0 = nc * 64;
  for (int c = tid; c < D_; c += 256) {
    float s = 0.0f;
    #pragma unroll 4
    for (int n = 0; n < 64; ++n)
      s += x[((size_t)(b*N_ + n0 + n))*D_ + c];
    ctxp[(size_t)(nc*B_ + b)*D_ + c] = s;
  }
}

// ---------------------------------------------------------------- mlp layer 1 (gelu)
// Batch-split: grid (12 j-chunks, 2 g/l, 8 batches) = 192 blocks. Folds its
// own batch's 32 ctx partials (32x768x4B = 98 KB, L2-hot) while filling hs.
__global__ __launch_bounds__(256) void k_mlp1(
    const float* __restrict__ ctxp,
    const float* __restrict__ w1g, const float* __restrict__ b1g,
    const float* __restrict__ w1l, const float* __restrict__ b1l,
    float* __restrict__ h1g, float* __restrict__ h1l) {
  __shared__ float hs[D_];
  __shared__ float red[4][16][5];
  const int tid = threadIdx.x;
  const bool isl = (blockIdx.y != 0);
  const int bb = blockIdx.z;
  const float* w1 = isl ? w1l : w1g;
  const float* b1 = isl ? b1l : b1g;
  float*       h1 = isl ? h1l : h1g;
  const int j0 = (int)blockIdx.x * 64;

  for (int i = tid; i < D_; i += 256) {
    float s = 0.0f;
    #pragma unroll 8
    for (int p = 0; p < 32; ++p)
      s += ctxp[(size_t)p*(B_*D_) + bb*D_ + i];
    hs[i] = s * (1.0f/(float)N_);
  }
  __syncthreads();

  const int jg    = tid & 15;
  const int slice = tid >> 4;
  const int j     = j0 + jg*4;
  float acc[4] = {};
  {
    const float4* w14 = (const float4*)w1;
    const int jc = j >> 2;
    const int i0 = slice*48;
    #pragma unroll 4
    for (int ii = 0; ii < 48; ++ii) {
      const int i = i0 + ii;
      const float4 w = w14[(size_t)i*192 + jc];
      const float hv = hs[i];
      acc[0] = fmaf(hv, w.x, acc[0]);
      acc[1] = fmaf(hv, w.y, acc[1]);
      acc[2] = fmaf(hv, w.z, acc[2]);
      acc[3] = fmaf(hv, w.w, acc[3]);
    }
  }
  #pragma unroll
  for (int q = 0; q < 4; ++q) {
    float v = acc[q];
    v += __shfl_xor(v, 16, 64);
    v += __shfl_xor(v, 32, 64);
    acc[q] = v;
  }
  const int wv = tid >> 6;
  if ((tid & 63) < 16) {
    #pragma unroll
    for (int q = 0; q < 4; ++q)
      red[wv][jg][q] = acc[q];
  }
  __syncthreads();
  if (tid < 64) {
    const int jg2 = tid >> 2;
    const int q   = tid & 3;
    const int jo  = j0 + jg2*4 + q;
    const float sum = red[0][jg2][q] + red[1][jg2][q]
                    + red[2][jg2][q] + red[3][jg2][q];
    const float v = sum + b1[jo];
    h1[(size_t)bb*D_ + jo] = 0.5f * v * (1.0f + erff(v * 0.70710678118654752f));
  }
}

// ---------------------------------------------------------------- mlp layer 2 (tanh)
__global__ __launch_bounds__(256) void k_mlp2(
    const float* __restrict__ h1g, const float* __restrict__ h1l,
    const float* __restrict__ w2g, const float* __restrict__ b2g,
    const float* __restrict__ w2l, const float* __restrict__ b2l,
    float* __restrict__ mg, float* __restrict__ ml) {
  __shared__ float hs[B_*D_];
  __shared__ float red[4][16][33];
  const int tid = threadIdx.x;
  const bool isg = (blockIdx.x < 193);
  const float* h1 = isg ? h1g : h1l;
  const float* w2 = isg ? w2g : w2l;
  const float* b2 = isg ? b2g : b2l;
  float*       mo = isg ? mg  : ml;
  const int Jmax = isg ? (H_*GB_) : (H_*LB_);
  const int j0   = isg ? (int)blockIdx.x*64 : ((int)blockIdx.x-193)*64;

  for (int i = tid; i < B_*D_; i += 256) hs[i] = h1[i];
  __syncthreads();

  const int jg    = tid & 15;
  const int slice = tid >> 4;
  const int j     = j0 + jg*4;
  float acc[8][4] = {};
  if (j < Jmax) {
    const float4* w24 = (const float4*)w2;
    const int jc   = j >> 2;
    const int rowq = Jmax >> 2;
    const int i0   = slice*48;
    #pragma unroll 4
    for (int ii = 0; ii < 48; ++ii) {
      const int i = i0 + ii;
      const float4 w = w24[(size_t)i*rowq + jc];
      #pragma unroll
      for (int b = 0; b < 8; ++b) {
        const float hv = hs[b*D_ + i];
        acc[b][0] = fmaf(hv, w.x, acc[b][0]);
        acc[b][1] = fmaf(hv, w.y, acc[b][1]);
        acc[b][2] = fmaf(hv, w.z, acc[b][2]);
        acc[b][3] = fmaf(hv, w.w, acc[b][3]);
      }
    }
  }
  #pragma unroll
  for (int b = 0; b < 8; ++b) {
    #pragma unroll
    for (int q = 0; q < 4; ++q) {
      float v = acc[b][q];
      v += __shfl_xor(v, 16, 64);
      v += __shfl_xor(v, 32, 64);
      acc[b][q] = v;
    }
  }
  const int wv = tid >> 6;
  if ((tid & 63) < 16) {
    #pragma unroll
    for (int b = 0; b < 8; ++b)
      #pragma unroll
      for (int q = 0; q < 4; ++q)
        red[wv][jg][b*4+q] = acc[b][q];
  }
  __syncthreads();
  for (int s = tid; s < 512; s += 256) {
    const int jg2 = s >> 5;
    const int v2  = s & 31;
    const int b   = v2 >> 2, q = v2 & 3;
    const int jo  = j0 + jg2*4 + q;
    if (jo < Jmax) {
      const float sum = red[0][jg2][v2] + red[1][jg2][v2]
                      + red[2][jg2][v2] + red[3][jg2][v2];
      mo[(size_t)b*Jmax + jo] = tanhf(sum + b2[jo]);
    }
  }
}

// ---------------------------------------------------------------- spectral
// One block per COLUMN QUAD. Output includes the RESIDUAL (re-reads x in the
// store phase); fused written in [cg][n][4] layout.
__global__ __launch_bounds__(256) void k_spectral(
    const float* __restrict__ x,
    const float* __restrict__ bfg, const float* __restrict__ bfl,
    const float* __restrict__ mbg, const float* __restrict__ mbl,
    const float* __restrict__ mg,  const float* __restrict__ ml,
    const float* __restrict__ fw,  float* __restrict__ fused) {
  __shared__ float4 cb[N_ + (N_>>4)];       // dual complex, swizzled (34.8 KB)
  __shared__ float2 tw[256 + 16];           // tw[TWX(m)] = exp(-i*pi*m/1024)
  __shared__ float  t1b[2][4][8], t2b[2][4][8];
  __shared__ float  lf[LB_], lb[LB_];

  const int tid = threadIdx.x;
  const int id  = blockIdx.x;               // 1536
  const int v_  = (id & 7) * 192 + (id >> 3);   // XCD-resident remap (1536/8=192)
  const int dq  = v_ & 15;
  const int bh  = v_ >> 4;
  const int h   = bh % H_;
  const int b   = bh / H_;
  const int d   = dq * 4;
  const int c   = h*HD_ + d;
  const int cg  = bh*16 + dq;               // channel-quad index

  {
    float s_, c_;
    sincospif(-(float)tid * (1.0f/1024.0f), &s_, &c_);
    tw[TWX(tid)] = make_float2(c_, s_);
  }
  if (tid < LB_) {
    lf[tid] = bfl[h*LB_ + tid] + ml[(size_t)b*(H_*LB_) + h*LB_ + tid];
    lb[tid] = mbl[h*LB_ + tid];
  }
  const float* xp = &x[((size_t)(b*N_))*D_ + c];
  for (int n = tid; n < N_; n += 256) {
    cb[CBX(n)] = *(const float4*)&xp[(size_t)n*D_];
  }
  __syncthreads();

  // ---- local windowed path (cb still holds raw x); two sequential passes ----
  const int lane = tid & 63, wvi = tid >> 6;
  float r1[8], r2[8], r3[8], r4[8];
  {
    float w1a[16], w2a[16];
    local_path<0>(cb, lf, lb, tid, w1a, w2a);
    if (lane == 63 && tid < NW_) {
      #pragma unroll
      for (int s = 0; s < 8; ++s) { t1b[0][wvi][s] = w1a[8+s]; t2b[0][wvi][s] = w2a[8+s]; }
    }
    __syncthreads();
    combine_oa(w1a, w2a, t1b[0], t2b[0], lane, wvi, r1, r2);
  }
  {
    float w1a[16], w2a[16];
    local_path<1>(cb, lf, lb, tid, w1a, w2a);
    if (lane == 63 && tid < NW_) {
      #pragma unroll
      for (int s = 0; s < 8; ++s) { t1b[1][wvi][s] = w1a[8+s]; t2b[1][wvi][s] = w2a[8+s]; }
    }
    __syncthreads();   // also guarantees all raw-x reads done before FFT writes
    combine_oa(w1a, w2a, t1b[1], t2b[1], lane, wvi, r3, r4);
  }

  // ---- forward FFT: 4 register trips (natural in -> bitrev out) ----
  fft_trip_fwd<256,8>(cb, tw, tid); __syncthreads();
  fft_trip_fwd< 32,5>(cb, tw, tid); __syncthreads();
  fft_trip_fwd<  4,2>(cb, tw, tid); __syncthreads();
  fft_trip4_fwd(cb, tid);           __syncthreads();

  // ---- separate packed spectra, filter+modrelu, repack (bitrev domain) ----
  const float fsc = 0.022097086912079610f;   // 1/sqrt(2048)
  {
    const float* mgp = mg + (size_t)b*(H_*GB_) + h*GB_;
    const float* bfp = bfg + h*GB_;
    const float* mbp = mbg + h*GB_;
    const int kb = (tid & 192) + (int)(__brev((unsigned)(tid & 63)) >> 26);  // brev6 lane permute
    #pragma unroll
    for (int t = 0; t < 4; ++t) {
      const int k = kb + 256*t;
      if (k == 0) {
        float4 Z0 = cb[CBX(0)], Zn = cb[CBX(1)];
        const float f0t = bfp[0] + mgp[0],     b0 = mbp[0];
        const float fnt = bfp[1024] + mgp[1024], bn = mbp[1024];
        float a0 = Z0.x*fsc, a1 = Z0.y*fsc, a2 = Z0.z*fsc, a3 = Z0.w*fsc;
        mr1(a0, f0t, b0); mr1(a1, f0t, b0); mr1(a2, f0t, b0); mr1(a3, f0t, b0);
        cb[CBX(0)] = make_float4(a0, a1, a2, a3);
        float n0v = Zn.x*fsc, n1v = Zn.y*fsc, n2v = Zn.z*fsc, n3v = Zn.w*fsc;
        mr1(n0v, fnt, bn); mr1(n1v, fnt, bn); mr1(n2v, fnt, bn); mr1(n3v, fnt, bn);
        cb[CBX(1)] = make_float4(n0v, n1v, n2v, n3v);
      } else {
        const int ik  = (int)(__brev((unsigned)k) >> 21);
        const int imk = (int)(__brev((unsigned)(2048 - k)) >> 21);
        const float4 Za = cb[CBX(ik)], Zb = cb[CBX(imk)];
        const float hs_ = 0.5f * fsc;
        const float filt = bfp[k] + mgp[k], bias = mbp[k];
        // pair 0 (.x,.y)
        float f1r = (Za.x + Zb.x) * hs_, f1i = (Za.y - Zb.y) * hs_;
        float f2r = (Za.y + Zb.y) * hs_, f2i = (Zb.x - Za.x) * hs_;
        mr2(f1r, f1i, filt, bias);
        mr2(f2r, f2i, filt, bias);
        // pair 1 (.z,.w)
        float g1r = (Za.z + Zb.z) * hs_, g1i = (Za.w - Zb.w) * hs_;
        float g2r = (Za.w + Zb.w) * hs_, g2i = (Zb.z - Za.z) * hs_;
        mr2(g1r, g1i, filt, bias);
        mr2(g2r, g2i, filt, bias);
        cb[CBX(ik)]  = make_float4(f1r - f2i, f1i + f2r, g1r - g2i, g1i + g2r);
        cb[CBX(imk)] = make_float4(f1r + f2i, f2r - f1i, g1r + g2i, g2r - g1i);
      }
    }
  }
  __syncthreads();

  // ---- inverse FFT: 4 register trips (bitrev in -> natural out) ----
  fft_trip1_inv(cb, tid);           __syncthreads();
  fft_trip_inv<  4,2>(cb, tw, tid); __syncthreads();
  fft_trip_inv< 32,5>(cb, tw, tid); __syncthreads();
  fft_trip_inv<256,8>(cb, tw, tid); __syncthreads();

  // ---- fuse + residual + store: thread j owns n in [8j, 8j+8) ----
  const float fw1v = fw[1];
  const float fwg  = fw[0] * fsc;
  float4* fo = (float4*)fused + (size_t)cg * N_;
  const int n0 = tid * 8;
  #pragma unroll
  for (int s = 0; s < 8; ++s) {
    const float4 g  = cb[CBX(n0 + s)];
    const float4 xv = *(const float4*)&xp[(size_t)(n0 + s)*D_];
    fo[n0 + s] = make_float4(xv.x + fwg * g.x + fw1v * r1[s],
                             xv.y + fwg * g.y + fw1v * r2[s],
                             xv.z + fwg * g.z + fw1v * r3[s],
                             xv.w + fwg * g.w + fw1v * r4[s]);
  }
}

// ---------------------------------------------------------------- LayerNorm
// fused already contains x + combined spectral output (residual done in
// k_spectral). 3 phases: load(transposed) -> row stats -> normalize.
__global__ __launch_bounds__(256) void k_ln(const float* __restrict__ fused,
                                            const float* __restrict__ gamma,
                                            const float* __restrict__ beta,
                                            float* __restrict__ out) {
  __shared__ float yt[16*776];     // stride 776: 776%32==8 -> limited conflicts
  __shared__ float mus[16], rsd[16];
  const int bi = blockIdx.x;
  const int b  = bi >> 7;
  const int n0 = (bi & 127) * 16;
  const int tid = threadIdx.x;

  {
    // fused layout [cg][n][4]: 16 consecutive threads read 256 B contiguous
    const float4* fu4 = (const float4*)fused;
    for (int i = tid; i < 16*192; i += 256) {
      const int cgl = i >> 4, rn = i & 15;
      const float4 g = fu4[((size_t)(b*192 + cgl))*N_ + n0 + rn];
      float* yp = &yt[rn*776 + cgl*4];
      yp[0] = g.x; yp[1] = g.y; yp[2] = g.z; yp[3] = g.w;
    }
  }
  __syncthreads();
  const int nn = tid >> 4, cl = tid & 15;
  float s1 = 0.0f, s2 = 0.0f;
  for (int c = cl; c < D_; c += 16) {
    const float v = yt[nn*776 + c];
    s1 += v; s2 += v*v;
  }
  #pragma unroll
  for (int m = 8; m >= 1; m >>= 1) {
    s1 += __shfl_xor(s1, m, 16);
    s2 += __shfl_xor(s2, m, 16);
  }
  if (cl == 0) {
    const float mu  = s1 * (1.0f/(float)D_);
    const float var = s2 * (1.0f/(float)D_) - mu*mu;
    mus[nn] = mu;
    rsd[nn] = rsqrtf(var + 1e-5f);
  }
  __syncthreads();
  {
    float4* o4 = (float4*)(out + ((size_t)(b*N_ + n0))*D_);
    const float4* g4 = (const float4*)gamma;
    const float4* be4 = (const float4*)beta;
    for (int i = tid; i < 16*D_/4; i += 256) {
      const int nn2 = i / 192, r = i - nn2*192;
      const float mu = mus[nn2], rs = rsd[nn2];
      const float4 gm = g4[r], bt = be4[r];
      const float* yp = &yt[nn2*776 + r*4];
      float4 o;
      o.x = (yp[0] - mu) * rs * gm.x + bt.x;
      o.y = (yp[1] - mu) * rs * gm.y + bt.y;
      o.z = (yp[2] - mu) * rs * gm.z + bt.z;
      o.w = (yp[3] - mu) * rs * gm.w + bt.w;
      o4[i] = o;
    }
  }
}

// ---------------------------------------------------------------- launch
extern "C" void kernel_launch(void* const* d_in, const int* in_sizes, int n_in,
                              void* d_out, int out_size, void* d_ws, size_t ws_size,
                              hipStream_t stream) {
  const float* x   = (const float*)d_in[0];
  const float* bfg = (const float*)d_in[1];
  const float* bfl = (const float*)d_in[2];
  const float* mbg = (const float*)d_in[3];
  const float* mbl = (const float*)d_in[4];
  const float* w1g = (const float*)d_in[5];
  const float* b1g = (const float*)d_in[6];
  const float* w2g = (const float*)d_in[7];
  const float* b2g = (const float*)d_in[8];
  const float* w1l = (const float*)d_in[9];
  const float* b1l = (const float*)d_in[10];
  const float* w2l = (const float*)d_in[11];
  const float* b2l = (const float*)d_in[12];
  const float* fw  = (const float*)d_in[13];
  const float* gam = (const float*)d_in[14];
  const float* bet = (const float*)d_in[15];
  float* out = (float*)d_out;

  float* ws    = (float*)d_ws;
  float* h1g   = ws + 6144;
  float* h1l   = ws + 12288;
  float* mg    = ws + 18432;         // 98400
  float* ml    = ws + 116832;        // 864
  float* fused = ws + 117696;        // 8*768*2048
  // ctxp (32 partials x B x D = 196608 floats) aliases the head of `fused`:
  // fully consumed by k_mlp1 BEFORE k_spectral writes fused (same stream).
  float* ctxp  = fused;

  k_ctx<<<dim3(B_, 32), 256, 0, stream>>>(x, ctxp);
  k_mlp1<<<dim3(12, 2, 8), 256, 0, stream>>>(ctxp, w1g, b1g, w1l, b1l, h1g, h1l);
  k_mlp2<<<195, 256, 0, stream>>>(h1g, h1l, w2g, b2g, w2l, b2l, mg, ml);
  k_spectral<<<B_*H_*16, 256, 0, stream>>>(x, bfg, bfl, mbg, mbl, mg, ml, fw, fused);
  k_ln<<<B_*N_/16, 256, 0, stream>>>(fused, gam, bet, out);
}

// Round 11
// 278.894 us; speedup vs baseline: 1.4465x; 1.0148x over previous
//
#include <hip/hip_runtime.h>
#include <math.h>

#define B_  8
#define N_  2048
#define D_  768
#define H_  12
#define HD_ 64
#define GB_ 1025
#define LB_ 9
#define NW_ 255

// LDS swizzles (bank-conflict breakers)
#define CBX(i) ((i) + ((i) >> 4))      // padded every 16 elements
#define TWX(i) ((i) + ((i) >> 4))      // twiddle table, same padding

// FFT16 constants
#define C1_ 0.92387953251128674f
#define S1_ 0.38268343236508978f
#define R2_ 0.70710678118654752f

// forward DIF butterflies (twiddle e^{-i*theta}) on yr/yi register arrays
#define FBF(i,k,wr,wi) { const float ar=yr[i],ai=yi[i],br=yr[k],bi=yi[k]; \
  yr[i]=ar+br; yi[i]=ai+bi; const float dr=ar-br, di=ai-bi; \
  yr[k]=fmaf(dr,wr,-(di*(wi))); yi[k]=fmaf(dr,wi,di*(wr)); }
#define FBF1(i,k) { const float ar=yr[i],ai=yi[i],br=yr[k],bi=yi[k]; \
  yr[i]=ar+br; yi[i]=ai+bi; yr[k]=ar-br; yi[k]=ai-bi; }
#define FBFmi(i,k) { const float ar=yr[i],ai=yi[i],br=yr[k],bi=yi[k]; \
  yr[i]=ar+br; yi[i]=ai+bi; yr[k]=ai-bi; yi[k]=br-ar; }

// inverse DIT butterflies (twiddle e^{+i*theta})
#define IBF(i,k,wr,wi) { const float br=yr[k],bi=yi[k]; \
  const float tr=fmaf(br,wr,-(bi*(wi))), ti=fmaf(br,wi,bi*(wr)); \
  yr[k]=yr[i]-tr; yi[k]=yi[i]-ti; yr[i]+=tr; yi[i]+=ti; }
#define IBF1(i,k) { const float tr=yr[k], ti=yi[k]; \
  yr[k]=yr[i]-tr; yi[k]=yi[i]-ti; yr[i]+=tr; yi[i]+=ti; }
#define IBFpi(i,k) { const float tr=-yi[k], ti=yr[k]; \
  yr[k]=yr[i]-tr; yi[k]=yi[i]-ti; yr[i]+=tr; yi[i]+=ti; }

__device__ __forceinline__ float2 cmulf(float2 a, float2 b) {
  return make_float2(fmaf(a.x, b.x, -(a.y*b.y)), fmaf(a.x, b.y, a.y*b.x));
}
__device__ __forceinline__ float2 csqf(float2 a){ return make_float2(fmaf(a.x,a.x,-(a.y*a.y)), 2.0f*a.x*a.y); }

// ---- dual packed complex (float4 = two complexes sharing one twiddle) ----
__device__ __forceinline__ float4 dadd(float4 a, float4 b){ return make_float4(a.x+b.x,a.y+b.y,a.z+b.z,a.w+b.w); }
__device__ __forceinline__ float4 dsub(float4 a, float4 b){ return make_float4(a.x-b.x,a.y-b.y,a.z-b.z,a.w-b.w); }
__device__ __forceinline__ float4 dmul(float4 a, float2 w){
  return make_float4(fmaf(a.x,w.x,-(a.y*w.y)), fmaf(a.x,w.y,a.y*w.x),
                     fmaf(a.z,w.x,-(a.w*w.y)), fmaf(a.z,w.y,a.w*w.x));
}
__device__ __forceinline__ float4 dmulc(float4 a, float2 w){   // * conj(w)
  return make_float4(fmaf(a.x,w.x,a.y*w.y), fmaf(a.y,w.x,-(a.x*w.y)),
                     fmaf(a.z,w.x,a.w*w.y), fmaf(a.w,w.x,-(a.z*w.y)));
}
__device__ __forceinline__ float4 dmuli(float4 a){  // * (-i)
  return make_float4(a.y, -a.x, a.w, -a.z);
}
__device__ __forceinline__ float4 dmulpi(float4 a){ // * (+i)
  return make_float4(-a.y, a.x, -a.w, a.z);
}

// modrelu helpers: native v_sqrt/v_rcp instead of precise-div chains
__device__ __forceinline__ void mr2(float& ar, float& ai, float filt, float bias){
  ar *= filt; ai *= filt;
  const float a = __builtin_amdgcn_sqrtf(fmaf(ar,ar,ai*ai));
  const float s = fmaxf(a + bias, 0.0f) * __builtin_amdgcn_rcpf(fmaxf(a, 1e-6f));
  ar *= s; ai *= s;
}
__device__ __forceinline__ void mr1(float& v, float filt, float bias){
  v *= filt;
  const float a = fabsf(v);
  v *= fmaxf(a + bias, 0.0f) * __builtin_amdgcn_rcpf(fmaxf(a, 1e-6f));
}

// ---- register FFT trips (dual): 3 radix-2 stages (spans 4S,2S,S) on the
// stride-S 8-value set owned by thread j. One tw read per trip; other
// twiddles derived exactly (c8 = e^{-i pi/4}, w^2, w^4, *(-i) free).
template<int S, int L>
__device__ __forceinline__ void fft_trip_fwd(float4* cb, const float2* tw, int j) {
  const int r    = j & (S-1);
  const int base = r + ((j >> L) << (L+3));
  float4 v[8];
  #pragma unroll
  for (int k = 0; k < 8; ++k) v[k] = cb[CBX(base + S*k)];
  const float2 w = tw[TWX(r * (256/S))];
  const float2 c8 = make_float2(R2_, -R2_);
  float2 W1[4];
  W1[0] = w;
  W1[1] = cmulf(w, c8);
  W1[2] = make_float2(w.y, -w.x);
  W1[3] = make_float2(W1[1].y, -W1[1].x);
  #pragma unroll
  for (int k = 0; k < 4; ++k) {
    const float4 u = v[k], t = v[k+4];
    v[k]   = dadd(u, t);
    v[k+4] = dmul(dsub(u, t), W1[k]);
  }
  const float2 w2  = csqf(w);
  const float2 w2i = make_float2(w2.y, -w2.x);
  {
    float4 d;
    d = dsub(v[0], v[2]); v[0] = dadd(v[0], v[2]); v[2] = dmul(d, w2);
    d = dsub(v[1], v[3]); v[1] = dadd(v[1], v[3]); v[3] = dmul(d, w2i);
    d = dsub(v[4], v[6]); v[4] = dadd(v[4], v[6]); v[6] = dmul(d, w2);
    d = dsub(v[5], v[7]); v[5] = dadd(v[5], v[7]); v[7] = dmul(d, w2i);
  }
  const float2 w4 = csqf(w2);
  #pragma unroll
  for (int k = 0; k < 8; k += 2) {
    const float4 d = dsub(v[k], v[k+1]);
    v[k]   = dadd(v[k], v[k+1]);
    v[k+1] = dmul(d, w4);
  }
  #pragma unroll
  for (int k = 0; k < 8; ++k) cb[CBX(base + S*k)] = v[k];
}

// final forward trip: spans 2,1 on 8 consecutive values (twiddle-free)
__device__ __forceinline__ void fft_trip4_fwd(float4* cb, int j) {
  const int base = j << 3;
  float4 v[8];
  #pragma unroll
  for (int k = 0; k < 8; ++k) v[k] = cb[CBX(base + k)];
  float4 d;
  d = dsub(v[0], v[2]); v[0] = dadd(v[0], v[2]); v[2] = d;
  d = dsub(v[1], v[3]); v[1] = dadd(v[1], v[3]); v[3] = dmuli(d);
  d = dsub(v[4], v[6]); v[4] = dadd(v[4], v[6]); v[6] = d;
  d = dsub(v[5], v[7]); v[5] = dadd(v[5], v[7]); v[7] = dmuli(d);
  #pragma unroll
  for (int k = 0; k < 8; k += 2) {
    d = dsub(v[k], v[k+1]);
    v[k]   = dadd(v[k], v[k+1]);
    v[k+1] = d;
  }
  #pragma unroll
  for (int k = 0; k < 8; ++k) cb[CBX(base + k)] = v[k];
}

// first inverse trip: spans 1,2 (conj twiddles trivial: 1, +i)
__device__ __forceinline__ void fft_trip1_inv(float4* cb, int j) {
  const int base = j << 3;
  float4 v[8];
  #pragma unroll
  for (int k = 0; k < 8; ++k) v[k] = cb[CBX(base + k)];
  #pragma unroll
  for (int k = 0; k < 8; k += 2) {
    const float4 t = v[k+1];
    v[k+1] = dsub(v[k], t);
    v[k]   = dadd(v[k], t);
  }
  {
    float4 t;
    t = v[2];          v[2] = dsub(v[0], t); v[0] = dadd(v[0], t);
    t = dmulpi(v[3]);  v[3] = dsub(v[1], t); v[1] = dadd(v[1], t);
    t = v[6];          v[6] = dsub(v[4], t); v[4] = dadd(v[4], t);
    t = dmulpi(v[7]);  v[7] = dsub(v[5], t); v[5] = dadd(v[5], t);
  }
  #pragma unroll
  for (int k = 0; k < 8; ++k) cb[CBX(base + k)] = v[k];
}

template<int S, int L>
__device__ __forceinline__ void fft_trip_inv(float4* cb, const float2* tw, int j) {
  const int r    = j & (S-1);
  const int base = r + ((j >> L) << (L+3));
  float4 v[8];
  #pragma unroll
  for (int k = 0; k < 8; ++k) v[k] = cb[CBX(base + S*k)];
  const float2 w  = tw[TWX(r * (256/S))];
  const float2 w2 = csqf(w);
  const float2 w4 = csqf(w2);
  #pragma unroll
  for (int k = 0; k < 8; k += 2) {
    const float4 t = dmulc(v[k+1], w4);
    v[k+1] = dsub(v[k], t);
    v[k]   = dadd(v[k], t);
  }
  {
    float4 t;
    t = dmulc(v[2], w2);          v[2] = dsub(v[0], t); v[0] = dadd(v[0], t);
    t = dmulpi(dmulc(v[3], w2));  v[3] = dsub(v[1], t); v[1] = dadd(v[1], t);
    t = dmulc(v[6], w2);          v[6] = dsub(v[4], t); v[4] = dadd(v[4], t);
    t = dmulpi(dmulc(v[7], w2));  v[7] = dsub(v[5], t); v[5] = dadd(v[5], t);
  }
  const float2 c8 = make_float2(R2_, -R2_);
  float2 W1[4];
  W1[0] = w;
  W1[1] = cmulf(w, c8);
  W1[2] = make_float2(w.y, -w.x);
  W1[3] = make_float2(W1[1].y, -W1[1].x);
  #pragma unroll
  for (int k = 0; k < 4; ++k) {
    const float4 t = dmulc(v[k+4], W1[k]);
    v[k+4] = dsub(v[k], t);
    v[k]   = dadd(v[k], t);
  }
  #pragma unroll
  for (int k = 0; k < 8; ++k) cb[CBX(base + S*k)] = v[k];
}

// ---- local windowed FFT16 path for one packed half (HALF=0 -> .xy, 1 -> .zw)
template<int HALF>
__device__ __forceinline__ void local_path(const float4* cb, const float* lf, const float* lb,
                                           int tid, float* w1a, float* w2a) {
  const float HWIN[16] = {0.0f, 0.038060233744356624f, 0.14644660940672624f, 0.30865828381745508f,
                          0.5f, 0.69134171618254492f, 0.85355339059327376f, 0.96193976625564337f,
                          1.0f, 0.96193976625564337f, 0.85355339059327376f, 0.69134171618254492f,
                          0.5f, 0.30865828381745508f, 0.14644660940672624f, 0.038060233744356624f};
  if (tid < NW_) {
    float yr[16], yi[16];
    #pragma unroll
    for (int t = 0; t < 16; ++t) {
      const float4 v = cb[CBX(tid*8 + t)];
      yr[t] = (HALF ? v.z : v.x) * HWIN[t];
      yi[t] = (HALF ? v.w : v.y) * HWIN[t];
    }
    // forward FFT16 (DIF, natural -> bitrev)
    FBF1(0,8); FBF(1,9,C1_,-S1_); FBF(2,10,R2_,-R2_); FBF(3,11,S1_,-C1_);
    FBFmi(4,12); FBF(5,13,-S1_,-C1_); FBF(6,14,-R2_,-R2_); FBF(7,15,-C1_,-S1_);
    FBF1(0,4); FBF(1,5,R2_,-R2_); FBFmi(2,6); FBF(3,7,-R2_,-R2_);
    FBF1(8,12); FBF(9,13,R2_,-R2_); FBFmi(10,14); FBF(11,15,-R2_,-R2_);
    FBF1(0,2); FBFmi(1,3); FBF1(4,6); FBFmi(5,7);
    FBF1(8,10); FBFmi(9,11); FBF1(12,14); FBFmi(13,15);
    FBF1(0,1); FBF1(2,3); FBF1(4,5); FBF1(6,7);
    FBF1(8,9); FBF1(10,11); FBF1(12,13); FBF1(14,15);
    // separate F1/F2 (bitrev), filter+modrelu, repack W (bitrev)
    {
      const int IA[9] = {0,8,4,12,2,10,6,14,1};
      const int IB[9] = {0,15,7,11,3,13,5,9,1};
      #pragma unroll
      for (int l = 0; l <= 8; ++l) {
        const int ia = IA[l], ib = IB[l];
        const float Zar=yr[ia], Zai=yi[ia], Zbr=yr[ib], Zbi=yi[ib];
        float f1r = 0.125f*(Zar+Zbr), f1i = 0.125f*(Zai-Zbi);
        float f2r = 0.125f*(Zai+Zbi), f2i = 0.125f*(Zbr-Zar);
        const float ft = lf[l], bs = lb[l];
        mr2(f1r, f1i, ft, bs);
        mr2(f2r, f2i, ft, bs);
        yr[ia] = f1r - f2i; yi[ia] = f1i + f2r;
        if (l >= 1 && l <= 7) { yr[ib] = f1r + f2i; yi[ib] = f2r - f1i; }
      }
    }
    // inverse FFT16 (DIT, bitrev -> natural)
    IBF1(0,1); IBF1(2,3); IBF1(4,5); IBF1(6,7);
    IBF1(8,9); IBF1(10,11); IBF1(12,13); IBF1(14,15);
    IBF1(0,2); IBFpi(1,3); IBF1(4,6); IBFpi(5,7);
    IBF1(8,10); IBFpi(9,11); IBF1(12,14); IBFpi(13,15);
    IBF1(0,4); IBF(1,5,R2_,R2_); IBFpi(2,6); IBF(3,7,-R2_,R2_);
    IBF1(8,12); IBF(9,13,R2_,R2_); IBFpi(10,14); IBF(11,15,-R2_,R2_);
    IBF1(0,8); IBF(1,9,C1_,S1_); IBF(2,10,R2_,R2_); IBF(3,11,S1_,C1_);
    IBFpi(4,12); IBF(5,13,-S1_,C1_); IBF(6,14,-R2_,R2_); IBF(7,15,-C1_,S1_);
    #pragma unroll
    for (int t = 0; t < 16; ++t) {
      const float q = 0.25f * HWIN[t];
      w1a[t] = yr[t] * q;
      w2a[t] = yi[t] * q;
    }
  } else {
    #pragma unroll
    for (int t = 0; t < 16; ++t) { w1a[t] = 0.0f; w2a[t] = 0.0f; }
  }
}

__device__ __forceinline__ void combine_oa(const float* w1a, const float* w2a,
                                           const float (*t1)[8], const float (*t2)[8],
                                           int lane, int wvi, float* r1, float* r2) {
  #pragma unroll
  for (int s = 0; s < 8; ++s) {
    float p1 = __shfl_up(w1a[s+8], 1, 64);
    float p2 = __shfl_up(w2a[s+8], 1, 64);
    if (lane == 0) {
      p1 = wvi ? t1[wvi-1][s] : 0.0f;
      p2 = wvi ? t2[wvi-1][s] : 0.0f;
    }
    r1[s] = w1a[s] + p1;
    r2[s] = w2a[s] + p2;
  }
}

// ---------------------------------------------------------------- ctx mean
// (contended atomics: measured best vs both partial-sum variants, R5/R10)
__global__ __launch_bounds__(256) void k_ctx(const float* __restrict__ x,
                                             float* __restrict__ ctx) {
  const int b = blockIdx.x;
  const int nc = blockIdx.y;
  const int tid = threadIdx.x;
  const int n0 = nc * 64;
  for (int c = tid; c < D_; c += 256) {
    float s = 0.0f;
    #pragma unroll 4
    for (int n = 0; n < 64; ++n)
      s += x[((size_t)(b*N_ + n0 + n))*D_ + c];
    atomicAdd(&ctx[b*D_ + c], s);
  }
}

// ---------------------------------------------------------------- mlp layer 1 (gelu)
// Batch-split: grid (12 j-chunks, 2 g/l, 8 batches) = 192 blocks.
__global__ __launch_bounds__(256) void k_mlp1(
    const float* __restrict__ ctx,
    const float* __restrict__ w1g, const float* __restrict__ b1g,
    const float* __restrict__ w1l, const float* __restrict__ b1l,
    float* __restrict__ h1g, float* __restrict__ h1l) {
  __shared__ float hs[D_];
  __shared__ float red[4][16][5];
  const int tid = threadIdx.x;
  const bool isl = (blockIdx.y != 0);
  const int bb = blockIdx.z;
  const float* w1 = isl ? w1l : w1g;
  const float* b1 = isl ? b1l : b1g;
  float*       h1 = isl ? h1l : h1g;
  const int j0 = (int)blockIdx.x * 64;

  for (int i = tid; i < D_; i += 256) hs[i] = ctx[bb*D_ + i] * (1.0f/(float)N_);
  __syncthreads();

  const int jg    = tid & 15;
  const int slice = tid >> 4;
  const int j     = j0 + jg*4;
  float acc[4] = {};
  {
    const float4* w14 = (const float4*)w1;
    const int jc = j >> 2;
    const int i0 = slice*48;
    #pragma unroll 4
    for (int ii = 0; ii < 48; ++ii) {
      const int i = i0 + ii;
      const float4 w = w14[(size_t)i*192 + jc];
      const float hv = hs[i];
      acc[0] = fmaf(hv, w.x, acc[0]);
      acc[1] = fmaf(hv, w.y, acc[1]);
      acc[2] = fmaf(hv, w.z, acc[2]);
      acc[3] = fmaf(hv, w.w, acc[3]);
    }
  }
  #pragma unroll
  for (int q = 0; q < 4; ++q) {
    float v = acc[q];
    v += __shfl_xor(v, 16, 64);
    v += __shfl_xor(v, 32, 64);
    acc[q] = v;
  }
  const int wv = tid >> 6;
  if ((tid & 63) < 16) {
    #pragma unroll
    for (int q = 0; q < 4; ++q)
      red[wv][jg][q] = acc[q];
  }
  __syncthreads();
  if (tid < 64) {
    const int jg2 = tid >> 2;
    const int q   = tid & 3;
    const int jo  = j0 + jg2*4 + q;
    const float sum = red[0][jg2][q] + red[1][jg2][q]
                    + red[2][jg2][q] + red[3][jg2][q];
    const float v = sum + b1[jo];
    h1[(size_t)bb*D_ + jo] = 0.5f * v * (1.0f + erff(v * 0.70710678118654752f));
  }
}

// ---------------------------------------------------------------- mlp layer 2 (tanh)
__global__ __launch_bounds__(256) void k_mlp2(
    const float* __restrict__ h1g, const float* __restrict__ h1l,
    const float* __restrict__ w2g, const float* __restrict__ b2g,
    const float* __restrict__ w2l, const float* __restrict__ b2l,
    float* __restrict__ mg, float* __restrict__ ml) {
  __shared__ float hs[B_*D_];
  __shared__ float red[4][16][33];
  const int tid = threadIdx.x;
  const bool isg = (blockIdx.x < 193);
  const float* h1 = isg ? h1g : h1l;
  const float* w2 = isg ? w2g : w2l;
  const float* b2 = isg ? b2g : b2l;
  float*       mo = isg ? mg  : ml;
  const int Jmax = isg ? (H_*GB_) : (H_*LB_);
  const int j0   = isg ? (int)blockIdx.x*64 : ((int)blockIdx.x-193)*64;

  for (int i = tid; i < B_*D_; i += 256) hs[i] = h1[i];
  __syncthreads();

  const int jg    = tid & 15;
  const int slice = tid >> 4;
  const int j     = j0 + jg*4;
  float acc[8][4] = {};
  if (j < Jmax) {
    const float4* w24 = (const float4*)w2;
    const int jc   = j >> 2;
    const int rowq = Jmax >> 2;
    const int i0   = slice*48;
    #pragma unroll 4
    for (int ii = 0; ii < 48; ++ii) {
      const int i = i0 + ii;
      const float4 w = w24[(size_t)i*rowq + jc];
      #pragma unroll
      for (int b = 0; b < 8; ++b) {
        const float hv = hs[b*D_ + i];
        acc[b][0] = fmaf(hv, w.x, acc[b][0]);
        acc[b][1] = fmaf(hv, w.y, acc[b][1]);
        acc[b][2] = fmaf(hv, w.z, acc[b][2]);
        acc[b][3] = fmaf(hv, w.w, acc[b][3]);
      }
    }
  }
  #pragma unroll
  for (int b = 0; b < 8; ++b) {
    #pragma unroll
    for (int q = 0; q < 4; ++q) {
      float v = acc[b][q];
      v += __shfl_xor(v, 16, 64);
      v += __shfl_xor(v, 32, 64);
      acc[b][q] = v;
    }
  }
  const int wv = tid >> 6;
  if ((tid & 63) < 16) {
    #pragma unroll
    for (int b = 0; b < 8; ++b)
      #pragma unroll
      for (int q = 0; q < 4; ++q)
        red[wv][jg][b*4+q] = acc[b][q];
  }
  __syncthreads();
  for (int s = tid; s < 512; s += 256) {
    const int jg2 = s >> 5;
    const int v2  = s & 31;
    const int b   = v2 >> 2, q = v2 & 3;
    const int jo  = j0 + jg2*4 + q;
    if (jo < Jmax) {
      const float sum = red[0][jg2][v2] + red[1][jg2][v2]
                      + red[2][jg2][v2] + red[3][jg2][v2];
      mo[(size_t)b*Jmax + jo] = tanhf(sum + b2[jo]);
    }
  }
}

// ---------------------------------------------------------------- spectral
// One block per COLUMN QUAD. Residual fused into the output WITHOUT a global
// x re-read: each thread stashes its 8 store-phase x values (still raw in cb
// before the FFT overwrites it) in registers (+32 VGPR, same occupancy bin).
// fused written in [cg][n][4] layout.
__global__ __launch_bounds__(256) void k_spectral(
    const float* __restrict__ x,
    const float* __restrict__ bfg, const float* __restrict__ bfl,
    const float* __restrict__ mbg, const float* __restrict__ mbl,
    const float* __restrict__ mg,  const float* __restrict__ ml,
    const float* __restrict__ fw,  float* __restrict__ fused) {
  __shared__ float4 cb[N_ + (N_>>4)];       // dual complex, swizzled (34.8 KB)
  __shared__ float2 tw[256 + 16];           // tw[TWX(m)] = exp(-i*pi*m/1024)
  __shared__ float  t1b[2][4][8], t2b[2][4][8];
  __shared__ float  lf[LB_], lb[LB_];

  const int tid = threadIdx.x;
  const int id  = blockIdx.x;               // 1536
  const int v_  = (id & 7) * 192 + (id >> 3);   // XCD-resident remap (1536/8=192)
  const int dq  = v_ & 15;
  const int bh  = v_ >> 4;
  const int h   = bh % H_;
  const int b   = bh / H_;
  const int d   = dq * 4;
  const int c   = h*HD_ + d;
  const int cg  = bh*16 + dq;               // channel-quad index

  {
    float s_, c_;
    sincospif(-(float)tid * (1.0f/1024.0f), &s_, &c_);
    tw[TWX(tid)] = make_float2(c_, s_);
  }
  if (tid < LB_) {
    lf[tid] = bfl[h*LB_ + tid] + ml[(size_t)b*(H_*LB_) + h*LB_ + tid];
    lb[tid] = mbl[h*LB_ + tid];
  }
  const float* xp = &x[((size_t)(b*N_))*D_ + c];
  for (int n = tid; n < N_; n += 256) {
    cb[CBX(n)] = *(const float4*)&xp[(size_t)n*D_];
  }
  __syncthreads();

  // ---- stash this thread's store-phase x rows (cb holds raw x) ----
  float4 xs[8];
  {
    const int n0 = tid * 8;
    #pragma unroll
    for (int s = 0; s < 8; ++s) xs[s] = cb[CBX(n0 + s)];
  }

  // ---- local windowed path (cb still holds raw x); two sequential passes ----
  const int lane = tid & 63, wvi = tid >> 6;
  float r1[8], r2[8], r3[8], r4[8];
  {
    float w1a[16], w2a[16];
    local_path<0>(cb, lf, lb, tid, w1a, w2a);
    if (lane == 63 && tid < NW_) {
      #pragma unroll
      for (int s = 0; s < 8; ++s) { t1b[0][wvi][s] = w1a[8+s]; t2b[0][wvi][s] = w2a[8+s]; }
    }
    __syncthreads();
    combine_oa(w1a, w2a, t1b[0], t2b[0], lane, wvi, r1, r2);
  }
  {
    float w1a[16], w2a[16];
    local_path<1>(cb, lf, lb, tid, w1a, w2a);
    if (lane == 63 && tid < NW_) {
      #pragma unroll
      for (int s = 0; s < 8; ++s) { t1b[1][wvi][s] = w1a[8+s]; t2b[1][wvi][s] = w2a[8+s]; }
    }
    __syncthreads();   // also guarantees all raw-x reads done before FFT writes
    combine_oa(w1a, w2a, t1b[1], t2b[1], lane, wvi, r3, r4);
  }

  // ---- forward FFT: 4 register trips (natural in -> bitrev out) ----
  fft_trip_fwd<256,8>(cb, tw, tid); __syncthreads();
  fft_trip_fwd< 32,5>(cb, tw, tid); __syncthreads();
  fft_trip_fwd<  4,2>(cb, tw, tid); __syncthreads();
  fft_trip4_fwd(cb, tid);           __syncthreads();

  // ---- separate packed spectra, filter+modrelu, repack (bitrev domain) ----
  const float fsc = 0.022097086912079610f;   // 1/sqrt(2048)
  {
    const float* mgp = mg + (size_t)b*(H_*GB_) + h*GB_;
    const float* bfp = bfg + h*GB_;
    const float* mbp = mbg + h*GB_;
    const int kb = (tid & 192) + (int)(__brev((unsigned)(tid & 63)) >> 26);  // brev6 lane permute
    #pragma unroll
    for (int t = 0; t < 4; ++t) {
      const int k = kb + 256*t;
      if (k == 0) {
        float4 Z0 = cb[CBX(0)], Zn = cb[CBX(1)];
        const float f0t = bfp[0] + mgp[0],     b0 = mbp[0];
        const float fnt = bfp[1024] + mgp[1024], bn = mbp[1024];
        float a0 = Z0.x*fsc, a1 = Z0.y*fsc, a2 = Z0.z*fsc, a3 = Z0.w*fsc;
        mr1(a0, f0t, b0); mr1(a1, f0t, b0); mr1(a2, f0t, b0); mr1(a3, f0t, b0);
        cb[CBX(0)] = make_float4(a0, a1, a2, a3);
        float n0v = Zn.x*fsc, n1v = Zn.y*fsc, n2v = Zn.z*fsc, n3v = Zn.w*fsc;
        mr1(n0v, fnt, bn); mr1(n1v, fnt, bn); mr1(n2v, fnt, bn); mr1(n3v, fnt, bn);
        cb[CBX(1)] = make_float4(n0v, n1v, n2v, n3v);
      } else {
        const int ik  = (int)(__brev((unsigned)k) >> 21);
        const int imk = (int)(__brev((unsigned)(2048 - k)) >> 21);
        const float4 Za = cb[CBX(ik)], Zb = cb[CBX(imk)];
        const float hs_ = 0.5f * fsc;
        const float filt = bfp[k] + mgp[k], bias = mbp[k];
        // pair 0 (.x,.y)
        float f1r = (Za.x + Zb.x) * hs_, f1i = (Za.y - Zb.y) * hs_;
        float f2r = (Za.y + Zb.y) * hs_, f2i = (Zb.x - Za.x) * hs_;
        mr2(f1r, f1i, filt, bias);
        mr2(f2r, f2i, filt, bias);
        // pair 1 (.z,.w)
        float g1r = (Za.z + Zb.z) * hs_, g1i = (Za.w - Zb.w) * hs_;
        float g2r = (Za.w + Zb.w) * hs_, g2i = (Zb.z - Za.z) * hs_;
        mr2(g1r, g1i, filt, bias);
        mr2(g2r, g2i, filt, bias);
        cb[CBX(ik)]  = make_float4(f1r - f2i, f1i + f2r, g1r - g2i, g1i + g2r);
        cb[CBX(imk)] = make_float4(f1r + f2i, f2r - f1i, g1r + g2i, g2r - g1i);
      }
    }
  }
  __syncthreads();

  // ---- inverse FFT: 4 register trips (bitrev in -> natural out) ----
  fft_trip1_inv(cb, tid);           __syncthreads();
  fft_trip_inv<  4,2>(cb, tw, tid); __syncthreads();
  fft_trip_inv< 32,5>(cb, tw, tid); __syncthreads();
  fft_trip_inv<256,8>(cb, tw, tid); __syncthreads();

  // ---- fuse + residual (from registers) + store ----
  const float fw1v = fw[1];
  const float fwg  = fw[0] * fsc;
  float4* fo = (float4*)fused + (size_t)cg * N_;
  const int n0 = tid * 8;
  #pragma unroll
  for (int s = 0; s < 8; ++s) {
    const float4 g  = cb[CBX(n0 + s)];
    fo[n0 + s] = make_float4(xs[s].x + fwg * g.x + fw1v * r1[s],
                             xs[s].y + fwg * g.y + fw1v * r2[s],
                             xs[s].z + fwg * g.z + fw1v * r3[s],
                             xs[s].w + fwg * g.w + fw1v * r4[s]);
  }
}

// ---------------------------------------------------------------- LayerNorm
// fused already contains x + combined spectral output (residual done in
// k_spectral). 3 phases: load(transposed) -> row stats -> normalize.
__global__ __launch_bounds__(256) void k_ln(const float* __restrict__ fused,
                                            const float* __restrict__ gamma,
                                            const float* __restrict__ beta,
                                            float* __restrict__ out) {
  __shared__ float yt[16*776];     // stride 776: 776%32==8 -> limited conflicts
  __shared__ float mus[16], rsd[16];
  const int bi = blockIdx.x;
  const int b  = bi >> 7;
  const int n0 = (bi & 127) * 16;
  const int tid = threadIdx.x;

  {
    // fused layout [cg][n][4]: 16 consecutive threads read 256 B contiguous
    const float4* fu4 = (const float4*)fused;
    for (int i = tid; i < 16*192; i += 256) {
      const int cgl = i >> 4, rn = i & 15;
      const float4 g = fu4[((size_t)(b*192 + cgl))*N_ + n0 + rn];
      float* yp = &yt[rn*776 + cgl*4];
      yp[0] = g.x; yp[1] = g.y; yp[2] = g.z; yp[3] = g.w;
    }
  }
  __syncthreads();
  const int nn = tid >> 4, cl = tid & 15;
  float s1 = 0.0f, s2 = 0.0f;
  for (int c = cl; c < D_; c += 16) {
    const float v = yt[nn*776 + c];
    s1 += v; s2 += v*v;
  }
  #pragma unroll
  for (int m = 8; m >= 1; m >>= 1) {
    s1 += __shfl_xor(s1, m, 16);
    s2 += __shfl_xor(s2, m, 16);
  }
  if (cl == 0) {
    const float mu  = s1 * (1.0f/(float)D_);
    const float var = s2 * (1.0f/(float)D_) - mu*mu;
    mus[nn] = mu;
    rsd[nn] = rsqrtf(var + 1e-5f);
  }
  __syncthreads();
  {
    float4* o4 = (float4*)(out + ((size_t)(b*N_ + n0))*D_);
    const float4* g4 = (const float4*)gamma;
    const float4* be4 = (const float4*)beta;
    for (int i = tid; i < 16*D_/4; i += 256) {
      const int nn2 = i / 192, r = i - nn2*192;
      const float mu = mus[nn2], rs = rsd[nn2];
      const float4 gm = g4[r], bt = be4[r];
      const float* yp = &yt[nn2*776 + r*4];
      float4 o;
      o.x = (yp[0] - mu) * rs * gm.x + bt.x;
      o.y = (yp[1] - mu) * rs * gm.y + bt.y;
      o.z = (yp[2] - mu) * rs * gm.z + bt.z;
      o.w = (yp[3] - mu) * rs * gm.w + bt.w;
      o4[i] = o;
    }
  }
}

// ---------------------------------------------------------------- launch
extern "C" void kernel_launch(void* const* d_in, const int* in_sizes, int n_in,
                              void* d_out, int out_size, void* d_ws, size_t ws_size,
                              hipStream_t stream) {
  const float* x   = (const float*)d_in[0];
  const float* bfg = (const float*)d_in[1];
  const float* bfl = (const float*)d_in[2];
  const float* mbg = (const float*)d_in[3];
  const float* mbl = (const float*)d_in[4];
  const float* w1g = (const float*)d_in[5];
  const float* b1g = (const float*)d_in[6];
  const float* w2g = (const float*)d_in[7];
  const float* b2g = (const float*)d_in[8];
  const float* w1l = (const float*)d_in[9];
  const float* b1l = (const float*)d_in[10];
  const float* w2l = (const float*)d_in[11];
  const float* b2l = (const float*)d_in[12];
  const float* fw  = (const float*)d_in[13];
  const float* gam = (const float*)d_in[14];
  const float* bet = (const float*)d_in[15];
  float* out = (float*)d_out;

  float* ws    = (float*)d_ws;
  float* ctx   = ws;                 // 6144
  float* h1g   = ws + 6144;
  float* h1l   = ws + 12288;
  float* mg    = ws + 18432;         // 98400
  float* ml    = ws + 116832;        // 864
  float* fused = ws + 117696;        // 8*768*2048

  hipMemsetAsync(ctx, 0, (size_t)B_*D_*sizeof(float), stream);
  k_ctx<<<dim3(B_, 32), 256, 0, stream>>>(x, ctx);
  k_mlp1<<<dim3(12, 2, 8), 256, 0, stream>>>(ctx, w1g, b1g, w1l, b1l, h1g, h1l);
  k_mlp2<<<195, 256, 0, stream>>>(h1g, h1l, w2g, b2g, w2l, b2l, mg, ml);
  k_spectral<<<B_*H_*16, 256, 0, stream>>>(x, bfg, bfl, mbg, mbl, mg, ml, fw, fused);
  k_ln<<<B_*N_/16, 256, 0, stream>>>(fused, gam, bet, out);
}